// Round 1
// baseline (1584.440 us; speedup 1.0000x reference)
//
#include <hip/hip_runtime.h>

#define N_NODES 262144
#define N_EDGES 8388608

typedef unsigned int uint32;
typedef unsigned short ushort16;

__device__ __forceinline__ float bf2f(uint32 u) { return __uint_as_float(u << 16); }
__device__ __forceinline__ ushort16 f2bf(float x) {
    uint32 u = __float_as_uint(x);
    u = (u + 0x7fffu + ((u >> 16) & 1u)) >> 16;
    return (ushort16)u;
}
__device__ __forceinline__ float lrelu(float v) { return v > 0.f ? v : 0.01f * v; }

// K1: agg[dst] += pos[src]  (segment_sum over edges)
__global__ __launch_bounds__(256) void k_scatter(const int* __restrict__ ei,
                                                 const float* __restrict__ pos,
                                                 float* __restrict__ agg) {
    int e = blockIdx.x * 256 + threadIdx.x;
    int s = ei[e];
    int d = ei[N_EDGES + e];
    const float* p = pos + 3 * s;
    float p0 = p[0], p1 = p[1], p2 = p[2];
    float* a = agg + 3 * d;
    atomicAdd(a + 0, p0);
    atomicAdd(a + 1, p1);
    atomicAdd(a + 2, p2);
}

// K2: y = (1+eps)*pos + agg; accumulate 9 moments of y (for analytic BN1)
__global__ __launch_bounds__(256) void k_y_moments(const float* __restrict__ pos,
                                                   const float* __restrict__ agg,
                                                   const float* __restrict__ epsp,
                                                   float* __restrict__ y,
                                                   float* __restrict__ mom) {
    int n = blockIdx.x * 256 + threadIdx.x;
    float e1 = 1.f + epsp[0];
    float y0 = e1 * pos[3 * n + 0] + agg[3 * n + 0];
    float y1 = e1 * pos[3 * n + 1] + agg[3 * n + 1];
    float y2 = e1 * pos[3 * n + 2] + agg[3 * n + 2];
    y[3 * n + 0] = y0; y[3 * n + 1] = y1; y[3 * n + 2] = y2;
    float m[9] = {y0, y1, y2, y0 * y0, y0 * y1, y0 * y2, y1 * y1, y1 * y2, y2 * y2};
    #pragma unroll
    for (int j = 0; j < 9; ++j) {
        #pragma unroll
        for (int o = 1; o < 64; o <<= 1) m[j] += __shfl_xor(m[j], o, 64);
    }
    __shared__ float buf[4][9];
    int lane = threadIdx.x & 63, wid = threadIdx.x >> 6;
    if (lane == 0) {
        #pragma unroll
        for (int j = 0; j < 9; ++j) buf[wid][j] = m[j];
    }
    __syncthreads();
    if (threadIdx.x < 9) {
        float s = buf[0][threadIdx.x] + buf[1][threadIdx.x] + buf[2][threadIdx.x] + buf[3][threadIdx.x];
        atomicAdd(&mom[threadIdx.x], s);
    }
}

// K3a: analytic BN1 -> fold BN+affine into A3 (3x128) and cvec (128)
__global__ __launch_bounds__(128) void k_bn1(const float* __restrict__ mom,
                                             const float* __restrict__ Wc,
                                             const float* __restrict__ bc,
                                             const float* __restrict__ g1,
                                             const float* __restrict__ be1,
                                             float* __restrict__ A3,
                                             float* __restrict__ cvec) {
    int d = threadIdx.x;
    float inv = 1.f / (float)N_NODES;
    float m0 = mom[0] * inv, m1 = mom[1] * inv, m2 = mom[2] * inv;
    float c00 = mom[3] * inv - m0 * m0;
    float c01 = mom[4] * inv - m0 * m1;
    float c02 = mom[5] * inv - m0 * m2;
    float c11 = mom[6] * inv - m1 * m1;
    float c12 = mom[7] * inv - m1 * m2;
    float c22 = mom[8] * inv - m2 * m2;
    float w0 = Wc[d], w1 = Wc[128 + d], w2 = Wc[256 + d];
    float mu = m0 * w0 + m1 * w1 + m2 * w2 + bc[d];
    float var = c00 * w0 * w0 + c11 * w1 * w1 + c22 * w2 * w2 +
                2.f * (c01 * w0 * w1 + c02 * w0 * w2 + c12 * w1 * w2);
    float s1 = g1[d] * rsqrtf(var + 1e-5f);
    float sh1 = be1[d] - mu * s1;
    A3[d] = w0 * s1;
    A3[128 + d] = w1 * s1;
    A3[256 + d] = w2 * s1;
    cvec[d] = bc[d] * s1 + sh1;
}

// K3b: E64b[c][d] = b1[d] + embed[c] @ W1_top  (embedding branch collapsed to 64x128 LUT)
__global__ __launch_bounds__(128) void k_e64(const float* __restrict__ emb,
                                             const float* __restrict__ W1,
                                             const float* __restrict__ b1,
                                             float* __restrict__ E64b) {
    int c = blockIdx.x, d = threadIdx.x;
    float acc = b1[d];
    for (int k = 0; k < 128; ++k) acc += emb[c * 128 + k] * W1[k * 128 + d];
    E64b[c * 128 + d] = acc;
}

// K4: main pass. MODE 0: h=bf16-store + BN2 stats; MODE 1: stats only; MODE 2: final output.
template <int MODE>
__global__ __launch_bounds__(256, 2) void k_main(const float* __restrict__ y,
                                                 const int* __restrict__ deg,
                                                 const float* __restrict__ A3,
                                                 const float* __restrict__ cvec,
                                                 const float* __restrict__ W1,
                                                 const float* __restrict__ E64b,
                                                 float* __restrict__ stat2,
                                                 ushort16* __restrict__ hout,
                                                 const float* __restrict__ sc2,
                                                 const float* __restrict__ sh2,
                                                 const float* __restrict__ W2,
                                                 const float* __restrict__ b2,
                                                 float* __restrict__ out) {
    __shared__ float Wl[128][128];   // W1_bot (rows 128..255 of fc_W1), 64 KB
    __shared__ float xl[32][128];    // x tile, 16 KB  (total 80 KB -> 2 blocks/CU)

    for (int i = threadIdx.x; i < 128 * 128; i += 256)
        Wl[i >> 7][i & 127] = W1[16384 + i];

    const int fg = threadIdx.x & 15;   // feature group (8 feats)
    const int np = threadIdx.x >> 4;   // node pair
    const int f0 = fg * 8;
    const int n0 = np * 2;
    const int fx = threadIdx.x & 127;
    const int nb = threadIdx.x >> 7;

    float a0 = A3[fx], a1 = A3[128 + fx], a2 = A3[256 + fx], cv = cvec[fx];
    float ssum[8] = {0}, ssq[8] = {0};

    float s2v[8], t2v[8], w2v[8], b2v = 0.f;
    if constexpr (MODE == 2) {
        *(float4*)&s2v[0] = *(const float4*)&sc2[f0];
        *(float4*)&s2v[4] = *(const float4*)&sc2[f0 + 4];
        *(float4*)&t2v[0] = *(const float4*)&sh2[f0];
        *(float4*)&t2v[4] = *(const float4*)&sh2[f0 + 4];
        *(float4*)&w2v[0] = *(const float4*)&W2[f0];
        *(float4*)&w2v[4] = *(const float4*)&W2[f0 + 4];
        b2v = b2[0];
    }

    for (int it = 0; it < 4; ++it) {
        int nbase = (blockIdx.x * 4 + it) * 32;
        __syncthreads();  // protect xl (and Wl on first iter)
        // stage x = lrelu(y @ A3 + cvec) into LDS
        #pragma unroll
        for (int s = 0; s < 16; ++s) {
            int n = nb + s * 2;
            const float* yy = y + (nbase + n) * 3;
            float v = yy[0] * a0 + yy[1] * a1 + yy[2] * a2 + cv;
            xl[n][fx] = lrelu(v);
        }
        __syncthreads();

        // register-blocked GEMM: 2 nodes x 8 feats per thread, K=128
        float acc0[8] = {0}, acc1[8] = {0};
        for (int k4 = 0; k4 < 32; ++k4) {
            float xs0[4], xs1[4];
            *(float4*)xs0 = *(const float4*)&xl[n0][k4 * 4];
            *(float4*)xs1 = *(const float4*)&xl[n0 + 1][k4 * 4];
            #pragma unroll
            for (int kk = 0; kk < 4; ++kk) {
                float4 wA = *(const float4*)&Wl[k4 * 4 + kk][f0];
                float4 wB = *(const float4*)&Wl[k4 * 4 + kk][f0 + 4];
                float xa = xs0[kk], xb = xs1[kk];
                acc0[0] += xa * wA.x; acc0[1] += xa * wA.y; acc0[2] += xa * wA.z; acc0[3] += xa * wA.w;
                acc0[4] += xa * wB.x; acc0[5] += xa * wB.y; acc0[6] += xa * wB.z; acc0[7] += xa * wB.w;
                acc1[0] += xb * wA.x; acc1[1] += xb * wA.y; acc1[2] += xb * wA.z; acc1[3] += xb * wA.w;
                acc1[4] += xb * wB.x; acc1[5] += xb * wB.y; acc1[6] += xb * wB.z; acc1[7] += xb * wB.w;
            }
        }

        int nA = nbase + n0, nB = nA + 1;
        int dA = deg[nA], dB = deg[nB];
        float eA[8], eB[8], hA[8], hB[8];
        *(float4*)&eA[0] = *(const float4*)&E64b[dA * 128 + f0];
        *(float4*)&eA[4] = *(const float4*)&E64b[dA * 128 + f0 + 4];
        *(float4*)&eB[0] = *(const float4*)&E64b[dB * 128 + f0];
        *(float4*)&eB[4] = *(const float4*)&E64b[dB * 128 + f0 + 4];
        #pragma unroll
        for (int j = 0; j < 8; ++j) { hA[j] = acc0[j] + eA[j]; hB[j] = acc1[j] + eB[j]; }

        if constexpr (MODE <= 1) {
            #pragma unroll
            for (int j = 0; j < 8; ++j) {
                ssum[j] += hA[j] + hB[j];
                ssq[j] += hA[j] * hA[j] + hB[j] * hB[j];
            }
        }
        if constexpr (MODE == 0) {
            uint32 pk[4];
            #pragma unroll
            for (int q = 0; q < 4; ++q)
                pk[q] = (uint32)f2bf(hA[2 * q]) | ((uint32)f2bf(hA[2 * q + 1]) << 16);
            *(uint4*)&hout[(size_t)nA * 128 + f0] = *(uint4*)pk;
            #pragma unroll
            for (int q = 0; q < 4; ++q)
                pk[q] = (uint32)f2bf(hB[2 * q]) | ((uint32)f2bf(hB[2 * q + 1]) << 16);
            *(uint4*)&hout[(size_t)nB * 128 + f0] = *(uint4*)pk;
        }
        if constexpr (MODE == 2) {
            float pA = 0.f, pB = 0.f;
            #pragma unroll
            for (int j = 0; j < 8; ++j) {
                pA += lrelu(hA[j] * s2v[j] + t2v[j]) * w2v[j];
                pB += lrelu(hB[j] * s2v[j] + t2v[j]) * w2v[j];
            }
            #pragma unroll
            for (int o = 1; o < 16; o <<= 1) {
                pA += __shfl_xor(pA, o, 64);
                pB += __shfl_xor(pB, o, 64);
            }
            if (fg == 0) {
                out[nA] = 1.f / (1.f + expf(-(pA + b2v)));
                out[nB] = 1.f / (1.f + expf(-(pB + b2v)));
            }
        }
    }

    if constexpr (MODE <= 1) {
        __syncthreads();
        #pragma unroll
        for (int j = 0; j < 8; ++j) {
            ssum[j] += __shfl_xor(ssum[j], 16, 64);
            ssum[j] += __shfl_xor(ssum[j], 32, 64);
            ssq[j] += __shfl_xor(ssq[j], 16, 64);
            ssq[j] += __shfl_xor(ssq[j], 32, 64);
        }
        float* redp = &xl[0][0];  // reuse LDS (post-barrier)
        int lane = threadIdx.x & 63, wid = threadIdx.x >> 6;
        if (lane < 16) {
            #pragma unroll
            for (int j = 0; j < 8; ++j) {
                redp[wid * 256 + lane * 16 + j] = ssum[j];
                redp[wid * 256 + lane * 16 + 8 + j] = ssq[j];
            }
        }
        __syncthreads();
        if (threadIdx.x < 128) {
            int d = threadIdx.x, fgg = d >> 3, j = d & 7;
            float s = redp[fgg * 16 + j] + redp[256 + fgg * 16 + j] +
                      redp[512 + fgg * 16 + j] + redp[768 + fgg * 16 + j];
            float q = redp[fgg * 16 + 8 + j] + redp[256 + fgg * 16 + 8 + j] +
                      redp[512 + fgg * 16 + 8 + j] + redp[768 + fgg * 16 + 8 + j];
            atomicAdd(&stat2[d], s);
            atomicAdd(&stat2[128 + d], q);
        }
    }
}

// K5: finalize BN2 scale/shift from stats
__global__ __launch_bounds__(128) void k_bn2(const float* __restrict__ stat2,
                                             const float* __restrict__ g2,
                                             const float* __restrict__ be2,
                                             float* __restrict__ sc2,
                                             float* __restrict__ sh2) {
    int d = threadIdx.x;
    float inv = 1.f / (float)N_NODES;
    float mu = stat2[d] * inv;
    float var = stat2[128 + d] * inv - mu * mu;
    float s = g2[d] * rsqrtf(var + 1e-5f);
    sc2[d] = s;
    sh2[d] = be2[d] - mu * s;
}

// K6: final elementwise from stored bf16 h: BN2 affine + lrelu + dot(W2) + sigmoid
__global__ __launch_bounds__(256) void k_final_h(const ushort16* __restrict__ h,
                                                 const float* __restrict__ sc2,
                                                 const float* __restrict__ sh2,
                                                 const float* __restrict__ W2,
                                                 const float* __restrict__ b2,
                                                 float* __restrict__ out) {
    int t = blockIdx.x * 256 + threadIdx.x;
    int node = t >> 3, part = t & 7;
    const ushort16* hp = h + (size_t)node * 128 + part * 16;
    uint32 ua[4], ub[4];
    *(uint4*)ua = *(const uint4*)hp;
    *(uint4*)ub = *(const uint4*)(hp + 8);
    int fb = part * 16;
    float pd = 0.f;
    #pragma unroll
    for (int q = 0; q < 4; ++q) {
        int f = fb + 2 * q;
        float v0 = bf2f(ua[q] & 0xffffu), v1 = bf2f(ua[q] >> 16);
        pd += lrelu(v0 * sc2[f] + sh2[f]) * W2[f];
        pd += lrelu(v1 * sc2[f + 1] + sh2[f + 1]) * W2[f + 1];
        int g = fb + 8 + 2 * q;
        float w0 = bf2f(ub[q] & 0xffffu), w1 = bf2f(ub[q] >> 16);
        pd += lrelu(w0 * sc2[g] + sh2[g]) * W2[g];
        pd += lrelu(w1 * sc2[g + 1] + sh2[g + 1]) * W2[g + 1];
    }
    pd += __shfl_xor(pd, 1, 64);
    pd += __shfl_xor(pd, 2, 64);
    pd += __shfl_xor(pd, 4, 64);
    if (part == 0) out[node] = 1.f / (1.f + expf(-(pd + b2[0])));
}

extern "C" void kernel_launch(void* const* d_in, const int* in_sizes, int n_in,
                              void* d_out, int out_size, void* d_ws, size_t ws_size,
                              hipStream_t stream) {
    const int*   node_deg = (const int*)d_in[0];
    const int*   ei       = (const int*)d_in[1];
    const float* pos      = (const float*)d_in[2];
    const float* emb      = (const float*)d_in[3];
    const float* epsp     = (const float*)d_in[4];
    const float* Wc       = (const float*)d_in[5];
    const float* bc       = (const float*)d_in[6];
    const float* g1       = (const float*)d_in[7];
    const float* be1      = (const float*)d_in[8];
    const float* W1       = (const float*)d_in[9];
    const float* b1       = (const float*)d_in[10];
    const float* g2       = (const float*)d_in[11];
    const float* be2      = (const float*)d_in[12];
    const float* W2       = (const float*)d_in[13];
    const float* b2       = (const float*)d_in[14];
    float* out = (float*)d_out;

    float* F = (float*)d_ws;
    float* agg   = F + 0;         // N*3 = 786432
    float* y     = F + 786432;    // N*3
    float* mom   = F + 1572864;   // 16
    float* stat2 = F + 1572880;   // 256
    float* A3    = F + 1573136;   // 384
    float* cvec  = F + 1573520;   // 128
    float* E64b  = F + 1573648;   // 8192
    float* sc2   = F + 1581840;   // 128
    float* sh2   = F + 1581968;   // 128
    ushort16* hbuf = (ushort16*)(F + 1582336);
    size_t need = (size_t)1582336 * 4 + (size_t)N_NODES * 128 * 2;
    bool storeH = ws_size >= need;

    hipMemsetAsync(agg, 0, 786432 * 4, stream);
    hipMemsetAsync(mom, 0, 272 * 4, stream);  // mom + stat2 contiguous

    k_scatter<<<N_EDGES / 256, 256, 0, stream>>>(ei, pos, agg);
    k_y_moments<<<N_NODES / 256, 256, 0, stream>>>(pos, agg, epsp, y, mom);
    k_bn1<<<1, 128, 0, stream>>>(mom, Wc, bc, g1, be1, A3, cvec);
    k_e64<<<64, 128, 0, stream>>>(emb, W1, b1, E64b);

    if (storeH) {
        k_main<0><<<2048, 256, 0, stream>>>(y, node_deg, A3, cvec, W1, E64b, stat2,
                                            hbuf, nullptr, nullptr, nullptr, nullptr, nullptr);
        k_bn2<<<1, 128, 0, stream>>>(stat2, g2, be2, sc2, sh2);
        k_final_h<<<N_NODES / 32, 256, 0, stream>>>(hbuf, sc2, sh2, W2, b2, out);
    } else {
        k_main<1><<<2048, 256, 0, stream>>>(y, node_deg, A3, cvec, W1, E64b, stat2,
                                            nullptr, nullptr, nullptr, nullptr, nullptr, nullptr);
        k_bn2<<<1, 128, 0, stream>>>(stat2, g2, be2, sc2, sh2);
        k_main<2><<<2048, 256, 0, stream>>>(y, node_deg, A3, cvec, W1, E64b, stat2,
                                            nullptr, sc2, sh2, W2, b2, out);
    }
}

// Round 2
// 1584.433 us; speedup vs baseline: 1.0000x; 1.0000x over previous
//
#include <hip/hip_runtime.h>

#define N_NODES 262144
#define N_EDGES 8388608

typedef unsigned int uint32;
typedef unsigned short ushort16;

__device__ __forceinline__ float bf2f(uint32 u) { return __uint_as_float(u << 16); }
__device__ __forceinline__ ushort16 f2bf(float x) {
    uint32 u = __float_as_uint(x);
    u = (u + 0x7fffu + ((u >> 16) & 1u)) >> 16;
    return (ushort16)u;
}
__device__ __forceinline__ float lrelu(float v) { return v > 0.f ? v : 0.01f * v; }

// K1: agg[dst] += pos[src]  (segment_sum over edges)
// R==8: per-XCD replica selected by physical XCC_ID; workgroup-scope atomics
// execute in the LOCAL TCC (stay cached in the XCD's L2) instead of the
// device-scope fabric path that cost 786 MB of write traffic in round 1.
// Correct because each replica is only ever touched by blocks on that XCD;
// end-of-kernel agent release writes the L2s back for the reduce kernel.
template <int R>
__global__ __launch_bounds__(256) void k_scatter(const int* __restrict__ ei,
                                                 const float* __restrict__ pos,
                                                 float* __restrict__ aggR) {
    int e = blockIdx.x * 256 + threadIdx.x;
    int s = ei[e];
    int d = ei[N_EDGES + e];
    const float* p = pos + 3 * s;
    float p0 = p[0], p1 = p[1], p2 = p[2];
    if constexpr (R == 8) {
        uint32 xcc;
        asm volatile("s_getreg_b32 %0, hwreg(HW_REG_XCC_ID)" : "=s"(xcc));
        float* a = aggR + (size_t)(xcc & 7u) * (3 * N_NODES) + 3 * d;
        __hip_atomic_fetch_add(a + 0, p0, __ATOMIC_RELAXED, __HIP_MEMORY_SCOPE_WORKGROUP);
        __hip_atomic_fetch_add(a + 1, p1, __ATOMIC_RELAXED, __HIP_MEMORY_SCOPE_WORKGROUP);
        __hip_atomic_fetch_add(a + 2, p2, __ATOMIC_RELAXED, __HIP_MEMORY_SCOPE_WORKGROUP);
    } else {
        float* a = aggR + 3 * d;
        atomicAdd(a + 0, p0);
        atomicAdd(a + 1, p1);
        atomicAdd(a + 2, p2);
    }
}

// K2: y = (1+eps)*pos + sum_r aggR; accumulate 9 moments of y (analytic BN1)
template <int R>
__global__ __launch_bounds__(256) void k_y_moments(const float* __restrict__ pos,
                                                   const float* __restrict__ aggR,
                                                   const float* __restrict__ epsp,
                                                   float* __restrict__ y,
                                                   float* __restrict__ mom) {
    int n = blockIdx.x * 256 + threadIdx.x;
    float e1 = 1.f + epsp[0];
    float a0 = 0.f, a1 = 0.f, a2 = 0.f;
    #pragma unroll
    for (int r = 0; r < R; ++r) {
        const float* A = aggR + (size_t)r * (3 * N_NODES) + 3 * n;
        a0 += A[0]; a1 += A[1]; a2 += A[2];
    }
    float y0 = e1 * pos[3 * n + 0] + a0;
    float y1 = e1 * pos[3 * n + 1] + a1;
    float y2 = e1 * pos[3 * n + 2] + a2;
    y[3 * n + 0] = y0; y[3 * n + 1] = y1; y[3 * n + 2] = y2;
    float m[9] = {y0, y1, y2, y0 * y0, y0 * y1, y0 * y2, y1 * y1, y1 * y2, y2 * y2};
    #pragma unroll
    for (int j = 0; j < 9; ++j) {
        #pragma unroll
        for (int o = 1; o < 64; o <<= 1) m[j] += __shfl_xor(m[j], o, 64);
    }
    __shared__ float buf[4][9];
    int lane = threadIdx.x & 63, wid = threadIdx.x >> 6;
    if (lane == 0) {
        #pragma unroll
        for (int j = 0; j < 9; ++j) buf[wid][j] = m[j];
    }
    __syncthreads();
    if (threadIdx.x < 9) {
        float s = buf[0][threadIdx.x] + buf[1][threadIdx.x] + buf[2][threadIdx.x] + buf[3][threadIdx.x];
        atomicAdd(&mom[threadIdx.x], s);
    }
}

// K3a: analytic BN1 -> fold BN+affine into A3 (3x128) and cvec (128)
__global__ __launch_bounds__(128) void k_bn1(const float* __restrict__ mom,
                                             const float* __restrict__ Wc,
                                             const float* __restrict__ bc,
                                             const float* __restrict__ g1,
                                             const float* __restrict__ be1,
                                             float* __restrict__ A3,
                                             float* __restrict__ cvec) {
    int d = threadIdx.x;
    float inv = 1.f / (float)N_NODES;
    float m0 = mom[0] * inv, m1 = mom[1] * inv, m2 = mom[2] * inv;
    float c00 = mom[3] * inv - m0 * m0;
    float c01 = mom[4] * inv - m0 * m1;
    float c02 = mom[5] * inv - m0 * m2;
    float c11 = mom[6] * inv - m1 * m1;
    float c12 = mom[7] * inv - m1 * m2;
    float c22 = mom[8] * inv - m2 * m2;
    float w0 = Wc[d], w1 = Wc[128 + d], w2 = Wc[256 + d];
    float mu = m0 * w0 + m1 * w1 + m2 * w2 + bc[d];
    float var = c00 * w0 * w0 + c11 * w1 * w1 + c22 * w2 * w2 +
                2.f * (c01 * w0 * w1 + c02 * w0 * w2 + c12 * w1 * w2);
    float s1 = g1[d] * rsqrtf(var + 1e-5f);
    float sh1 = be1[d] - mu * s1;
    A3[d] = w0 * s1;
    A3[128 + d] = w1 * s1;
    A3[256 + d] = w2 * s1;
    cvec[d] = bc[d] * s1 + sh1;
}

// K3b: E64b[c][d] = b1[d] + embed[c] @ W1_top  (embedding branch -> 64x128 LUT)
__global__ __launch_bounds__(128) void k_e64(const float* __restrict__ emb,
                                             const float* __restrict__ W1,
                                             const float* __restrict__ b1,
                                             float* __restrict__ E64b) {
    int c = blockIdx.x, d = threadIdx.x;
    float acc = b1[d];
    for (int k = 0; k < 128; ++k) acc += emb[c * 128 + k] * W1[k * 128 + d];
    E64b[c * 128 + d] = acc;
}

// K4: main pass. MODE 0: h=bf16-store + BN2 stats; MODE 1: stats only; MODE 2: final output.
template <int MODE>
__global__ __launch_bounds__(256, 2) void k_main(const float* __restrict__ y,
                                                 const int* __restrict__ deg,
                                                 const float* __restrict__ A3,
                                                 const float* __restrict__ cvec,
                                                 const float* __restrict__ W1,
                                                 const float* __restrict__ E64b,
                                                 float* __restrict__ stat2,
                                                 ushort16* __restrict__ hout,
                                                 const float* __restrict__ sc2,
                                                 const float* __restrict__ sh2,
                                                 const float* __restrict__ W2,
                                                 const float* __restrict__ b2,
                                                 float* __restrict__ out) {
    __shared__ float Wl[128][128];   // W1_bot (rows 128..255 of fc_W1), 64 KB
    __shared__ float xl[32][128];    // x tile, 16 KB  (total 80 KB -> 2 blocks/CU)

    for (int i = threadIdx.x; i < 128 * 128; i += 256)
        Wl[i >> 7][i & 127] = W1[16384 + i];

    const int fg = threadIdx.x & 15;   // feature group (8 feats)
    const int np = threadIdx.x >> 4;   // node pair
    const int f0 = fg * 8;
    const int n0 = np * 2;
    const int fx = threadIdx.x & 127;
    const int nb = threadIdx.x >> 7;

    float a0 = A3[fx], a1 = A3[128 + fx], a2 = A3[256 + fx], cv = cvec[fx];
    float ssum[8] = {0}, ssq[8] = {0};

    float s2v[8], t2v[8], w2v[8], b2v = 0.f;
    if constexpr (MODE == 2) {
        *(float4*)&s2v[0] = *(const float4*)&sc2[f0];
        *(float4*)&s2v[4] = *(const float4*)&sc2[f0 + 4];
        *(float4*)&t2v[0] = *(const float4*)&sh2[f0];
        *(float4*)&t2v[4] = *(const float4*)&sh2[f0 + 4];
        *(float4*)&w2v[0] = *(const float4*)&W2[f0];
        *(float4*)&w2v[4] = *(const float4*)&W2[f0 + 4];
        b2v = b2[0];
    }

    for (int it = 0; it < 4; ++it) {
        int nbase = (blockIdx.x * 4 + it) * 32;
        __syncthreads();  // protect xl (and Wl on first iter)
        // stage x = lrelu(y @ A3 + cvec) into LDS
        #pragma unroll
        for (int s = 0; s < 16; ++s) {
            int n = nb + s * 2;
            const float* yy = y + (nbase + n) * 3;
            float v = yy[0] * a0 + yy[1] * a1 + yy[2] * a2 + cv;
            xl[n][fx] = lrelu(v);
        }
        __syncthreads();

        // register-blocked GEMM: 2 nodes x 8 feats per thread, K=128
        float acc0[8] = {0}, acc1[8] = {0};
        for (int k4 = 0; k4 < 32; ++k4) {
            float xs0[4], xs1[4];
            *(float4*)xs0 = *(const float4*)&xl[n0][k4 * 4];
            *(float4*)xs1 = *(const float4*)&xl[n0 + 1][k4 * 4];
            #pragma unroll
            for (int kk = 0; kk < 4; ++kk) {
                float4 wA = *(const float4*)&Wl[k4 * 4 + kk][f0];
                float4 wB = *(const float4*)&Wl[k4 * 4 + kk][f0 + 4];
                float xa = xs0[kk], xb = xs1[kk];
                acc0[0] += xa * wA.x; acc0[1] += xa * wA.y; acc0[2] += xa * wA.z; acc0[3] += xa * wA.w;
                acc0[4] += xa * wB.x; acc0[5] += xa * wB.y; acc0[6] += xa * wB.z; acc0[7] += xa * wB.w;
                acc1[0] += xb * wA.x; acc1[1] += xb * wA.y; acc1[2] += xb * wA.z; acc1[3] += xb * wA.w;
                acc1[4] += xb * wB.x; acc1[5] += xb * wB.y; acc1[6] += xb * wB.z; acc1[7] += xb * wB.w;
            }
        }

        int nA = nbase + n0, nB = nA + 1;
        int dA = deg[nA], dB = deg[nB];
        float eA[8], eB[8], hA[8], hB[8];
        *(float4*)&eA[0] = *(const float4*)&E64b[dA * 128 + f0];
        *(float4*)&eA[4] = *(const float4*)&E64b[dA * 128 + f0 + 4];
        *(float4*)&eB[0] = *(const float4*)&E64b[dB * 128 + f0];
        *(float4*)&eB[4] = *(const float4*)&E64b[dB * 128 + f0 + 4];
        #pragma unroll
        for (int j = 0; j < 8; ++j) { hA[j] = acc0[j] + eA[j]; hB[j] = acc1[j] + eB[j]; }

        if constexpr (MODE <= 1) {
            #pragma unroll
            for (int j = 0; j < 8; ++j) {
                ssum[j] += hA[j] + hB[j];
                ssq[j] += hA[j] * hA[j] + hB[j] * hB[j];
            }
        }
        if constexpr (MODE == 0) {
            uint32 pk[4];
            #pragma unroll
            for (int q = 0; q < 4; ++q)
                pk[q] = (uint32)f2bf(hA[2 * q]) | ((uint32)f2bf(hA[2 * q + 1]) << 16);
            *(uint4*)&hout[(size_t)nA * 128 + f0] = *(uint4*)pk;
            #pragma unroll
            for (int q = 0; q < 4; ++q)
                pk[q] = (uint32)f2bf(hB[2 * q]) | ((uint32)f2bf(hB[2 * q + 1]) << 16);
            *(uint4*)&hout[(size_t)nB * 128 + f0] = *(uint4*)pk;
        }
        if constexpr (MODE == 2) {
            float pA = 0.f, pB = 0.f;
            #pragma unroll
            for (int j = 0; j < 8; ++j) {
                pA += lrelu(hA[j] * s2v[j] + t2v[j]) * w2v[j];
                pB += lrelu(hB[j] * s2v[j] + t2v[j]) * w2v[j];
            }
            #pragma unroll
            for (int o = 1; o < 16; o <<= 1) {
                pA += __shfl_xor(pA, o, 64);
                pB += __shfl_xor(pB, o, 64);
            }
            if (fg == 0) {
                out[nA] = 1.f / (1.f + expf(-(pA + b2v)));
                out[nB] = 1.f / (1.f + expf(-(pB + b2v)));
            }
        }
    }

    if constexpr (MODE <= 1) {
        __syncthreads();
        #pragma unroll
        for (int j = 0; j < 8; ++j) {
            ssum[j] += __shfl_xor(ssum[j], 16, 64);
            ssum[j] += __shfl_xor(ssum[j], 32, 64);
            ssq[j] += __shfl_xor(ssq[j], 16, 64);
            ssq[j] += __shfl_xor(ssq[j], 32, 64);
        }
        float* redp = &xl[0][0];  // reuse LDS (post-barrier)
        int lane = threadIdx.x & 63, wid = threadIdx.x >> 6;
        if (lane < 16) {
            #pragma unroll
            for (int j = 0; j < 8; ++j) {
                redp[wid * 256 + lane * 16 + j] = ssum[j];
                redp[wid * 256 + lane * 16 + 8 + j] = ssq[j];
            }
        }
        __syncthreads();
        if (threadIdx.x < 128) {
            int d = threadIdx.x, fgg = d >> 3, j = d & 7;
            float s = redp[fgg * 16 + j] + redp[256 + fgg * 16 + j] +
                      redp[512 + fgg * 16 + j] + redp[768 + fgg * 16 + j];
            float q = redp[fgg * 16 + 8 + j] + redp[256 + fgg * 16 + 8 + j] +
                      redp[512 + fgg * 16 + 8 + j] + redp[768 + fgg * 16 + 8 + j];
            atomicAdd(&stat2[d], s);
            atomicAdd(&stat2[128 + d], q);
        }
    }
}

// K5: finalize BN2 scale/shift from stats
__global__ __launch_bounds__(128) void k_bn2(const float* __restrict__ stat2,
                                             const float* __restrict__ g2,
                                             const float* __restrict__ be2,
                                             float* __restrict__ sc2,
                                             float* __restrict__ sh2) {
    int d = threadIdx.x;
    float inv = 1.f / (float)N_NODES;
    float mu = stat2[d] * inv;
    float var = stat2[128 + d] * inv - mu * mu;
    float s = g2[d] * rsqrtf(var + 1e-5f);
    sc2[d] = s;
    sh2[d] = be2[d] - mu * s;
}

// K6: final elementwise from stored bf16 h: BN2 affine + lrelu + dot(W2) + sigmoid
__global__ __launch_bounds__(256) void k_final_h(const ushort16* __restrict__ h,
                                                 const float* __restrict__ sc2,
                                                 const float* __restrict__ sh2,
                                                 const float* __restrict__ W2,
                                                 const float* __restrict__ b2,
                                                 float* __restrict__ out) {
    int t = blockIdx.x * 256 + threadIdx.x;
    int node = t >> 3, part = t & 7;
    const ushort16* hp = h + (size_t)node * 128 + part * 16;
    uint32 ua[4], ub[4];
    *(uint4*)ua = *(const uint4*)hp;
    *(uint4*)ub = *(const uint4*)(hp + 8);
    int fb = part * 16;
    float pd = 0.f;
    #pragma unroll
    for (int q = 0; q < 4; ++q) {
        int f = fb + 2 * q;
        float v0 = bf2f(ua[q] & 0xffffu), v1 = bf2f(ua[q] >> 16);
        pd += lrelu(v0 * sc2[f] + sh2[f]) * W2[f];
        pd += lrelu(v1 * sc2[f + 1] + sh2[f + 1]) * W2[f + 1];
        int g = fb + 8 + 2 * q;
        float w0 = bf2f(ub[q] & 0xffffu), w1 = bf2f(ub[q] >> 16);
        pd += lrelu(w0 * sc2[g] + sh2[g]) * W2[g];
        pd += lrelu(w1 * sc2[g + 1] + sh2[g + 1]) * W2[g + 1];
    }
    pd += __shfl_xor(pd, 1, 64);
    pd += __shfl_xor(pd, 2, 64);
    pd += __shfl_xor(pd, 4, 64);
    if (part == 0) out[node] = 1.f / (1.f + expf(-(pd + b2[0])));
}

extern "C" void kernel_launch(void* const* d_in, const int* in_sizes, int n_in,
                              void* d_out, int out_size, void* d_ws, size_t ws_size,
                              hipStream_t stream) {
    const int*   node_deg = (const int*)d_in[0];
    const int*   ei       = (const int*)d_in[1];
    const float* pos      = (const float*)d_in[2];
    const float* emb      = (const float*)d_in[3];
    const float* epsp     = (const float*)d_in[4];
    const float* Wc       = (const float*)d_in[5];
    const float* bc       = (const float*)d_in[6];
    const float* g1       = (const float*)d_in[7];
    const float* be1      = (const float*)d_in[8];
    const float* W1       = (const float*)d_in[9];
    const float* b1       = (const float*)d_in[10];
    const float* g2       = (const float*)d_in[11];
    const float* be2      = (const float*)d_in[12];
    const float* W2       = (const float*)d_in[13];
    const float* b2       = (const float*)d_in[14];
    float* out = (float*)d_out;

    // workspace sizing: prefer 8 per-XCD agg replicas (saves ~1.1ms of
    // fabric atomics) over the bf16 h-store (saves ~1 GEMM pass).
    auto needB = [](int R, bool sh) {
        return (size_t)((size_t)R * 786432 + 786432 + 9232) * 4 +
               (sh ? (size_t)N_NODES * 128 * 2 : 0);
    };
    int R; bool storeH;
    if      (ws_size >= needB(8, true))  { R = 8; storeH = true;  }
    else if (ws_size >= needB(8, false)) { R = 8; storeH = false; }
    else if (ws_size >= needB(1, true))  { R = 1; storeH = true;  }
    else                                 { R = 1; storeH = false; }

    float* F = (float*)d_ws;
    float* aggR  = F;                                  // R * N*3
    float* y     = aggR + (size_t)R * 786432;          // N*3
    float* mom   = y + 786432;                         // 16
    float* stat2 = mom + 16;                           // 256
    float* A3    = stat2 + 256;                        // 384
    float* cvec  = A3 + 384;                           // 128
    float* E64b  = cvec + 128;                         // 8192
    float* sc2   = E64b + 8192;                        // 128
    float* sh2   = sc2 + 128;                          // 128
    ushort16* hbuf = (ushort16*)(sh2 + 128);

    hipMemsetAsync(aggR, 0, (size_t)R * 786432 * 4, stream);
    hipMemsetAsync(mom, 0, 272 * 4, stream);  // mom + stat2 contiguous

    if (R == 8) {
        k_scatter<8><<<N_EDGES / 256, 256, 0, stream>>>(ei, pos, aggR);
        k_y_moments<8><<<N_NODES / 256, 256, 0, stream>>>(pos, aggR, epsp, y, mom);
    } else {
        k_scatter<1><<<N_EDGES / 256, 256, 0, stream>>>(ei, pos, aggR);
        k_y_moments<1><<<N_NODES / 256, 256, 0, stream>>>(pos, aggR, epsp, y, mom);
    }
    k_bn1<<<1, 128, 0, stream>>>(mom, Wc, bc, g1, be1, A3, cvec);
    k_e64<<<64, 128, 0, stream>>>(emb, W1, b1, E64b);

    if (storeH) {
        k_main<0><<<2048, 256, 0, stream>>>(y, node_deg, A3, cvec, W1, E64b, stat2,
                                            hbuf, nullptr, nullptr, nullptr, nullptr, nullptr);
        k_bn2<<<1, 128, 0, stream>>>(stat2, g2, be2, sc2, sh2);
        k_final_h<<<N_NODES / 32, 256, 0, stream>>>(hbuf, sc2, sh2, W2, b2, out);
    } else {
        k_main<1><<<2048, 256, 0, stream>>>(y, node_deg, A3, cvec, W1, E64b, stat2,
                                            nullptr, nullptr, nullptr, nullptr, nullptr, nullptr);
        k_bn2<<<1, 128, 0, stream>>>(stat2, g2, be2, sc2, sh2);
        k_main<2><<<2048, 256, 0, stream>>>(y, node_deg, A3, cvec, W1, E64b, stat2,
                                            nullptr, sc2, sh2, W2, b2, out);
    }
}

// Round 3
// 673.851 us; speedup vs baseline: 2.3513x; 2.3513x over previous
//
#include <hip/hip_runtime.h>

#define N_NODES 262144
#define N_EDGES 8388608
#define EPB 8192          // edges per block in binning passes
#define NBLK (N_EDGES / EPB)   // 1024 binning blocks
#define NBKT 1024         // buckets; 256 nodes each (N = 1024*256)

typedef unsigned int uint32;
typedef unsigned short ushort16;

__device__ __forceinline__ float bf2f(uint32 u) { return __uint_as_float(u << 16); }
__device__ __forceinline__ ushort16 f2bf(float x) {
    uint32 u = __float_as_uint(x);
    u = (u + 0x7fffu + ((u >> 16) & 1u)) >> 16;
    return (ushort16)u;
}
__device__ __forceinline__ float lrelu(float v) { return v > 0.f ? v : 0.01f * v; }

// ---------------- binning scatter (zero global atomics) ----------------
// Round-2 lesson: fp32 global atomics execute at the fabric coherence point
// regardless of instruction scope (~20.6 G/s, 32 B fabric traffic each).
// So we eliminate them: histogram -> exact scan offsets -> bucket-contiguous
// binned edges -> per-bucket LDS accumulation with exclusive agg writes.

// A: per-block histogram of dst buckets
__global__ __launch_bounds__(256) void k_hist(const int* __restrict__ ei,
                                              uint32* __restrict__ counts) {
    __shared__ uint32 cnt[NBKT];
    int t = threadIdx.x;
    for (int j = t; j < NBKT; j += 256) cnt[j] = 0;
    __syncthreads();
    int base = blockIdx.x * EPB;
    for (int ch = 0; ch < EPB / 256; ++ch) {
        int d = ei[N_EDGES + base + ch * 256 + t];
        atomicAdd(&cnt[d >> 8], 1u);
    }
    __syncthreads();
    for (int j = t; j < NBKT; j += 256) counts[blockIdx.x * NBKT + j] = cnt[j];
}

// B1: per-bucket exclusive scan over the 1024 block counts -> offsL, btot
__global__ __launch_bounds__(256) void k_scanB(const uint32* __restrict__ counts,
                                               uint32* __restrict__ offsL,
                                               uint32* __restrict__ btot) {
    int b = blockIdx.x, t = threadIdx.x;
    uint32 a[4], s = 0;
    #pragma unroll
    for (int j = 0; j < 4; ++j) { a[j] = counts[(4 * t + j) * NBKT + b]; s += a[j]; }
    int lane = t & 63, wid = t >> 6;
    uint32 v = s;
    #pragma unroll
    for (int o = 1; o < 64; o <<= 1) {
        uint32 u = __shfl_up(v, o, 64);
        if (lane >= o) v += u;
    }
    __shared__ uint32 wt[4];
    if (lane == 63) wt[wid] = v;
    __syncthreads();
    uint32 wbase = 0;
    for (int w = 0; w < wid; ++w) wbase += wt[w];
    uint32 run = wbase + v - s;   // exclusive prefix for this thread's first blk
    #pragma unroll
    for (int j = 0; j < 4; ++j) { offsL[(4 * t + j) * NBKT + b] = run; run += a[j]; }
    if (t == 255) btot[b] = run;
}

// B2: exclusive scan of 1024 bucket totals -> bucket start offsets
__global__ __launch_bounds__(256) void k_scanTot(const uint32* __restrict__ btot,
                                                 uint32* __restrict__ bstart) {
    int t = threadIdx.x;
    uint32 c[4], s = 0;
    #pragma unroll
    for (int j = 0; j < 4; ++j) { c[j] = btot[t * 4 + j]; s += c[j]; }
    int lane = t & 63, wid = t >> 6;
    uint32 v = s;
    #pragma unroll
    for (int o = 1; o < 64; o <<= 1) {
        uint32 u = __shfl_up(v, o, 64);
        if (lane >= o) v += u;
    }
    __shared__ uint32 wt[4];
    if (lane == 63) wt[wid] = v;
    __syncthreads();
    uint32 wbase = 0;
    for (int w = 0; w < wid; ++w) wbase += wt[w];
    uint32 run = wbase + v - s;
    #pragma unroll
    for (int j = 0; j < 4; ++j) { bstart[t * 4 + j] = run; run += c[j]; }
}

// C: write bucket-contiguous payloads (src<<8 | dstLocal); rank via LDS atomics
__global__ __launch_bounds__(256) void k_bin(const int* __restrict__ ei,
                                             const uint32* __restrict__ offsL,
                                             const uint32* __restrict__ bstart,
                                             uint32* __restrict__ binned) {
    __shared__ uint32 cnt[NBKT];
    __shared__ uint32 base[NBKT];
    int t = threadIdx.x;
    for (int j = t; j < NBKT; j += 256) {
        cnt[j] = 0;
        base[j] = bstart[j] + offsL[blockIdx.x * NBKT + j];
    }
    __syncthreads();
    int eb = blockIdx.x * EPB;
    for (int ch = 0; ch < EPB / 256; ++ch) {
        int e = eb + ch * 256 + t;
        uint32 s = (uint32)ei[e];
        uint32 d = (uint32)ei[N_EDGES + e];
        uint32 b = d >> 8;
        uint32 r = atomicAdd(&cnt[b], 1u);
        binned[base[b] + r] = (s << 8) | (d & 255u);
    }
}

// D: one block per bucket; accumulate in LDS, write agg slice exclusively
__global__ __launch_bounds__(256) void k_accum(const uint32* __restrict__ binned,
                                               const uint32* __restrict__ bstart,
                                               const uint32* __restrict__ btot,
                                               const float* __restrict__ pos,
                                               float* __restrict__ agg) {
    __shared__ float acc[768];
    int t = threadIdx.x;
    acc[t] = 0.f; acc[256 + t] = 0.f; acc[512 + t] = 0.f;
    __syncthreads();
    int b = blockIdx.x;
    uint32 st = bstart[b], ct = btot[b];
    for (uint32 i = t; i < ct; i += 256) {
        uint32 w = binned[st + i];
        uint32 s = w >> 8, dl = w & 255u;
        const float* p = pos + 3 * s;
        float p0 = p[0], p1 = p[1], p2 = p[2];
        atomicAdd(&acc[dl * 3 + 0], p0);
        atomicAdd(&acc[dl * 3 + 1], p1);
        atomicAdd(&acc[dl * 3 + 2], p2);
    }
    __syncthreads();
    float* o = agg + (size_t)b * 768;
    o[t] = acc[t]; o[256 + t] = acc[256 + t]; o[512 + t] = acc[512 + t];
}

// fallback: plain atomic scatter (used only if workspace is too small)
__global__ __launch_bounds__(256) void k_scatter(const int* __restrict__ ei,
                                                 const float* __restrict__ pos,
                                                 float* __restrict__ agg) {
    int e = blockIdx.x * 256 + threadIdx.x;
    int s = ei[e];
    int d = ei[N_EDGES + e];
    const float* p = pos + 3 * s;
    float* a = agg + 3 * d;
    atomicAdd(a + 0, p[0]);
    atomicAdd(a + 1, p[1]);
    atomicAdd(a + 2, p[2]);
}

// K2: y = (1+eps)*pos + agg; accumulate 9 moments of y (analytic BN1)
__global__ __launch_bounds__(256) void k_y_moments(const float* __restrict__ pos,
                                                   const float* __restrict__ agg,
                                                   const float* __restrict__ epsp,
                                                   float* __restrict__ y,
                                                   float* __restrict__ mom) {
    int n = blockIdx.x * 256 + threadIdx.x;
    float e1 = 1.f + epsp[0];
    float y0 = e1 * pos[3 * n + 0] + agg[3 * n + 0];
    float y1 = e1 * pos[3 * n + 1] + agg[3 * n + 1];
    float y2 = e1 * pos[3 * n + 2] + agg[3 * n + 2];
    y[3 * n + 0] = y0; y[3 * n + 1] = y1; y[3 * n + 2] = y2;
    float m[9] = {y0, y1, y2, y0 * y0, y0 * y1, y0 * y2, y1 * y1, y1 * y2, y2 * y2};
    #pragma unroll
    for (int j = 0; j < 9; ++j) {
        #pragma unroll
        for (int o = 1; o < 64; o <<= 1) m[j] += __shfl_xor(m[j], o, 64);
    }
    __shared__ float buf[4][9];
    int lane = threadIdx.x & 63, wid = threadIdx.x >> 6;
    if (lane == 0) {
        #pragma unroll
        for (int j = 0; j < 9; ++j) buf[wid][j] = m[j];
    }
    __syncthreads();
    if (threadIdx.x < 9) {
        float s = buf[0][threadIdx.x] + buf[1][threadIdx.x] + buf[2][threadIdx.x] + buf[3][threadIdx.x];
        atomicAdd(&mom[threadIdx.x], s);
    }
}

// K3a: analytic BN1 -> fold BN+affine into A3 (3x128) and cvec (128)
__global__ __launch_bounds__(128) void k_bn1(const float* __restrict__ mom,
                                             const float* __restrict__ Wc,
                                             const float* __restrict__ bc,
                                             const float* __restrict__ g1,
                                             const float* __restrict__ be1,
                                             float* __restrict__ A3,
                                             float* __restrict__ cvec) {
    int d = threadIdx.x;
    float inv = 1.f / (float)N_NODES;
    float m0 = mom[0] * inv, m1 = mom[1] * inv, m2 = mom[2] * inv;
    float c00 = mom[3] * inv - m0 * m0;
    float c01 = mom[4] * inv - m0 * m1;
    float c02 = mom[5] * inv - m0 * m2;
    float c11 = mom[6] * inv - m1 * m1;
    float c12 = mom[7] * inv - m1 * m2;
    float c22 = mom[8] * inv - m2 * m2;
    float w0 = Wc[d], w1 = Wc[128 + d], w2 = Wc[256 + d];
    float mu = m0 * w0 + m1 * w1 + m2 * w2 + bc[d];
    float var = c00 * w0 * w0 + c11 * w1 * w1 + c22 * w2 * w2 +
                2.f * (c01 * w0 * w1 + c02 * w0 * w2 + c12 * w1 * w2);
    float s1 = g1[d] * rsqrtf(var + 1e-5f);
    float sh1 = be1[d] - mu * s1;
    A3[d] = w0 * s1;
    A3[128 + d] = w1 * s1;
    A3[256 + d] = w2 * s1;
    cvec[d] = bc[d] * s1 + sh1;
}

// K3b: E64b[c][d] = b1[d] + embed[c] @ W1_top  (embedding branch -> 64x128 LUT)
__global__ __launch_bounds__(128) void k_e64(const float* __restrict__ emb,
                                             const float* __restrict__ W1,
                                             const float* __restrict__ b1,
                                             float* __restrict__ E64b) {
    int c = blockIdx.x, d = threadIdx.x;
    float acc = b1[d];
    for (int k = 0; k < 128; ++k) acc += emb[c * 128 + k] * W1[k * 128 + d];
    E64b[c * 128 + d] = acc;
}

// K4: main pass. MODE 0: h=bf16-store + BN2 stats; MODE 1: stats only; MODE 2: final output.
template <int MODE>
__global__ __launch_bounds__(256, 2) void k_main(const float* __restrict__ y,
                                                 const int* __restrict__ deg,
                                                 const float* __restrict__ A3,
                                                 const float* __restrict__ cvec,
                                                 const float* __restrict__ W1,
                                                 const float* __restrict__ E64b,
                                                 float* __restrict__ stat2,
                                                 ushort16* __restrict__ hout,
                                                 const float* __restrict__ sc2,
                                                 const float* __restrict__ sh2,
                                                 const float* __restrict__ W2,
                                                 const float* __restrict__ b2,
                                                 float* __restrict__ out) {
    __shared__ float Wl[128][128];   // W1_bot (rows 128..255 of fc_W1), 64 KB
    __shared__ float xl[32][128];    // x tile, 16 KB  (total 80 KB -> 2 blocks/CU)

    for (int i = threadIdx.x; i < 128 * 128; i += 256)
        Wl[i >> 7][i & 127] = W1[16384 + i];

    const int fg = threadIdx.x & 15;   // feature group (8 feats)
    const int np = threadIdx.x >> 4;   // node pair
    const int f0 = fg * 8;
    const int n0 = np * 2;
    const int fx = threadIdx.x & 127;
    const int nb = threadIdx.x >> 7;

    float a0 = A3[fx], a1 = A3[128 + fx], a2 = A3[256 + fx], cv = cvec[fx];
    float ssum[8] = {0}, ssq[8] = {0};

    float s2v[8], t2v[8], w2v[8], b2v = 0.f;
    if constexpr (MODE == 2) {
        *(float4*)&s2v[0] = *(const float4*)&sc2[f0];
        *(float4*)&s2v[4] = *(const float4*)&sc2[f0 + 4];
        *(float4*)&t2v[0] = *(const float4*)&sh2[f0];
        *(float4*)&t2v[4] = *(const float4*)&sh2[f0 + 4];
        *(float4*)&w2v[0] = *(const float4*)&W2[f0];
        *(float4*)&w2v[4] = *(const float4*)&W2[f0 + 4];
        b2v = b2[0];
    }

    for (int it = 0; it < 4; ++it) {
        int nbase = (blockIdx.x * 4 + it) * 32;
        __syncthreads();  // protect xl (and Wl on first iter)
        #pragma unroll
        for (int s = 0; s < 16; ++s) {
            int n = nb + s * 2;
            const float* yy = y + (nbase + n) * 3;
            float v = yy[0] * a0 + yy[1] * a1 + yy[2] * a2 + cv;
            xl[n][fx] = lrelu(v);
        }
        __syncthreads();

        float acc0[8] = {0}, acc1[8] = {0};
        for (int k4 = 0; k4 < 32; ++k4) {
            float xs0[4], xs1[4];
            *(float4*)xs0 = *(const float4*)&xl[n0][k4 * 4];
            *(float4*)xs1 = *(const float4*)&xl[n0 + 1][k4 * 4];
            #pragma unroll
            for (int kk = 0; kk < 4; ++kk) {
                float4 wA = *(const float4*)&Wl[k4 * 4 + kk][f0];
                float4 wB = *(const float4*)&Wl[k4 * 4 + kk][f0 + 4];
                float xa = xs0[kk], xb = xs1[kk];
                acc0[0] += xa * wA.x; acc0[1] += xa * wA.y; acc0[2] += xa * wA.z; acc0[3] += xa * wA.w;
                acc0[4] += xa * wB.x; acc0[5] += xa * wB.y; acc0[6] += xa * wB.z; acc0[7] += xa * wB.w;
                acc1[0] += xb * wA.x; acc1[1] += xb * wA.y; acc1[2] += xb * wA.z; acc1[3] += xb * wA.w;
                acc1[4] += xb * wB.x; acc1[5] += xb * wB.y; acc1[6] += xb * wB.z; acc1[7] += xb * wB.w;
            }
        }

        int nA = nbase + n0, nB = nA + 1;
        int dA = deg[nA], dB = deg[nB];
        float eA[8], eB[8], hA[8], hB[8];
        *(float4*)&eA[0] = *(const float4*)&E64b[dA * 128 + f0];
        *(float4*)&eA[4] = *(const float4*)&E64b[dA * 128 + f0 + 4];
        *(float4*)&eB[0] = *(const float4*)&E64b[dB * 128 + f0];
        *(float4*)&eB[4] = *(const float4*)&E64b[dB * 128 + f0 + 4];
        #pragma unroll
        for (int j = 0; j < 8; ++j) { hA[j] = acc0[j] + eA[j]; hB[j] = acc1[j] + eB[j]; }

        if constexpr (MODE <= 1) {
            #pragma unroll
            for (int j = 0; j < 8; ++j) {
                ssum[j] += hA[j] + hB[j];
                ssq[j] += hA[j] * hA[j] + hB[j] * hB[j];
            }
        }
        if constexpr (MODE == 0) {
            uint32 pk[4];
            #pragma unroll
            for (int q = 0; q < 4; ++q)
                pk[q] = (uint32)f2bf(hA[2 * q]) | ((uint32)f2bf(hA[2 * q + 1]) << 16);
            *(uint4*)&hout[(size_t)nA * 128 + f0] = *(uint4*)pk;
            #pragma unroll
            for (int q = 0; q < 4; ++q)
                pk[q] = (uint32)f2bf(hB[2 * q]) | ((uint32)f2bf(hB[2 * q + 1]) << 16);
            *(uint4*)&hout[(size_t)nB * 128 + f0] = *(uint4*)pk;
        }
        if constexpr (MODE == 2) {
            float pA = 0.f, pB = 0.f;
            #pragma unroll
            for (int j = 0; j < 8; ++j) {
                pA += lrelu(hA[j] * s2v[j] + t2v[j]) * w2v[j];
                pB += lrelu(hB[j] * s2v[j] + t2v[j]) * w2v[j];
            }
            #pragma unroll
            for (int o = 1; o < 16; o <<= 1) {
                pA += __shfl_xor(pA, o, 64);
                pB += __shfl_xor(pB, o, 64);
            }
            if (fg == 0) {
                out[nA] = 1.f / (1.f + expf(-(pA + b2v)));
                out[nB] = 1.f / (1.f + expf(-(pB + b2v)));
            }
        }
    }

    if constexpr (MODE <= 1) {
        __syncthreads();
        #pragma unroll
        for (int j = 0; j < 8; ++j) {
            ssum[j] += __shfl_xor(ssum[j], 16, 64);
            ssum[j] += __shfl_xor(ssum[j], 32, 64);
            ssq[j] += __shfl_xor(ssq[j], 16, 64);
            ssq[j] += __shfl_xor(ssq[j], 32, 64);
        }
        float* redp = &xl[0][0];  // reuse LDS (post-barrier)
        int lane = threadIdx.x & 63, wid = threadIdx.x >> 6;
        if (lane < 16) {
            #pragma unroll
            for (int j = 0; j < 8; ++j) {
                redp[wid * 256 + lane * 16 + j] = ssum[j];
                redp[wid * 256 + lane * 16 + 8 + j] = ssq[j];
            }
        }
        __syncthreads();
        if (threadIdx.x < 128) {
            int d = threadIdx.x, fgg = d >> 3, j = d & 7;
            float s = redp[fgg * 16 + j] + redp[256 + fgg * 16 + j] +
                      redp[512 + fgg * 16 + j] + redp[768 + fgg * 16 + j];
            float q = redp[fgg * 16 + 8 + j] + redp[256 + fgg * 16 + 8 + j] +
                      redp[512 + fgg * 16 + 8 + j] + redp[768 + fgg * 16 + 8 + j];
            atomicAdd(&stat2[d], s);
            atomicAdd(&stat2[128 + d], q);
        }
    }
}

// K5: finalize BN2 scale/shift from stats
__global__ __launch_bounds__(128) void k_bn2(const float* __restrict__ stat2,
                                             const float* __restrict__ g2,
                                             const float* __restrict__ be2,
                                             float* __restrict__ sc2,
                                             float* __restrict__ sh2) {
    int d = threadIdx.x;
    float inv = 1.f / (float)N_NODES;
    float mu = stat2[d] * inv;
    float var = stat2[128 + d] * inv - mu * mu;
    float s = g2[d] * rsqrtf(var + 1e-5f);
    sc2[d] = s;
    sh2[d] = be2[d] - mu * s;
}

// K6: final elementwise from stored bf16 h: BN2 affine + lrelu + dot(W2) + sigmoid
__global__ __launch_bounds__(256) void k_final_h(const ushort16* __restrict__ h,
                                                 const float* __restrict__ sc2,
                                                 const float* __restrict__ sh2,
                                                 const float* __restrict__ W2,
                                                 const float* __restrict__ b2,
                                                 float* __restrict__ out) {
    int t = blockIdx.x * 256 + threadIdx.x;
    int node = t >> 3, part = t & 7;
    const ushort16* hp = h + (size_t)node * 128 + part * 16;
    uint32 ua[4], ub[4];
    *(uint4*)ua = *(const uint4*)hp;
    *(uint4*)ub = *(const uint4*)(hp + 8);
    int fb = part * 16;
    float pd = 0.f;
    #pragma unroll
    for (int q = 0; q < 4; ++q) {
        int f = fb + 2 * q;
        float v0 = bf2f(ua[q] & 0xffffu), v1 = bf2f(ua[q] >> 16);
        pd += lrelu(v0 * sc2[f] + sh2[f]) * W2[f];
        pd += lrelu(v1 * sc2[f + 1] + sh2[f + 1]) * W2[f + 1];
        int g = fb + 8 + 2 * q;
        float w0 = bf2f(ub[q] & 0xffffu), w1 = bf2f(ub[q] >> 16);
        pd += lrelu(w0 * sc2[g] + sh2[g]) * W2[g];
        pd += lrelu(w1 * sc2[g + 1] + sh2[g + 1]) * W2[g + 1];
    }
    pd += __shfl_xor(pd, 1, 64);
    pd += __shfl_xor(pd, 2, 64);
    pd += __shfl_xor(pd, 4, 64);
    if (part == 0) out[node] = 1.f / (1.f + expf(-(pd + b2[0])));
}

extern "C" void kernel_launch(void* const* d_in, const int* in_sizes, int n_in,
                              void* d_out, int out_size, void* d_ws, size_t ws_size,
                              hipStream_t stream) {
    const int*   node_deg = (const int*)d_in[0];
    const int*   ei       = (const int*)d_in[1];
    const float* pos      = (const float*)d_in[2];
    const float* emb      = (const float*)d_in[3];
    const float* epsp     = (const float*)d_in[4];
    const float* Wc       = (const float*)d_in[5];
    const float* bc       = (const float*)d_in[6];
    const float* g1       = (const float*)d_in[7];
    const float* be1      = (const float*)d_in[8];
    const float* W1       = (const float*)d_in[9];
    const float* b1       = (const float*)d_in[10];
    const float* g2       = (const float*)d_in[11];
    const float* be2      = (const float*)d_in[12];
    const float* W2       = (const float*)d_in[13];
    const float* b2       = (const float*)d_in[14];
    float* out = (float*)d_out;

    // ---- workspace layout (float slots) ----
    float* F = (float*)d_ws;
    float* agg    = F;                    // 786432
    float* y      = F + 786432;           // 786432
    float* mom    = F + 1572864;          // 16
    float* stat2  = F + 1572880;          // 256
    float* A3     = F + 1573136;          // 384
    float* cvec   = F + 1573520;          // 128
    float* E64b   = F + 1573648;          // 8192
    float* sc2    = F + 1581840;          // 128
    float* sh2    = F + 1581968;          // 128
    uint32* bstart = (uint32*)(F + 1582096);  // 1024
    uint32* btot   = (uint32*)(F + 1583120);  // 1024
    float* U      = F + 1584144;          // overlay region
    uint32* binned = (uint32*)U;                        // 8388608 u32
    uint32* counts = (uint32*)(U + 8388608);            // 1048576 u32
    uint32* offsL  = (uint32*)(U + 9437184);            // 1048576 u32
    ushort16* hbuf = (ushort16*)U;  // aliases binned (dead after k_accum)

    const size_t needBinH  = (size_t)(1584144 + 16777216) * 4;  // 73,445,440
    const size_t needBin   = (size_t)(1584144 + 10485760) * 4;  // 48,279,616
    bool useBin, storeH;
    if      (ws_size >= needBinH) { useBin = true;  storeH = true;  }
    else if (ws_size >= needBin)  { useBin = true;  storeH = false; }
    else                          { useBin = false; storeH = false; }

    hipMemsetAsync(mom, 0, 272 * 4, stream);  // mom + stat2 contiguous

    if (useBin) {
        k_hist<<<NBLK, 256, 0, stream>>>(ei, counts);
        k_scanB<<<NBKT, 256, 0, stream>>>(counts, offsL, btot);
        k_scanTot<<<1, 256, 0, stream>>>(btot, bstart);
        k_bin<<<NBLK, 256, 0, stream>>>(ei, offsL, bstart, binned);
        k_accum<<<NBKT, 256, 0, stream>>>(binned, bstart, btot, pos, agg);
    } else {
        hipMemsetAsync(agg, 0, 786432 * 4, stream);
        k_scatter<<<N_EDGES / 256, 256, 0, stream>>>(ei, pos, agg);
    }
    k_y_moments<<<N_NODES / 256, 256, 0, stream>>>(pos, agg, epsp, y, mom);
    k_bn1<<<1, 128, 0, stream>>>(mom, Wc, bc, g1, be1, A3, cvec);
    k_e64<<<64, 128, 0, stream>>>(emb, W1, b1, E64b);

    if (storeH) {
        k_main<0><<<2048, 256, 0, stream>>>(y, node_deg, A3, cvec, W1, E64b, stat2,
                                            hbuf, nullptr, nullptr, nullptr, nullptr, nullptr);
        k_bn2<<<1, 128, 0, stream>>>(stat2, g2, be2, sc2, sh2);
        k_final_h<<<N_NODES / 32, 256, 0, stream>>>(hbuf, sc2, sh2, W2, b2, out);
    } else {
        k_main<1><<<2048, 256, 0, stream>>>(y, node_deg, A3, cvec, W1, E64b, stat2,
                                            nullptr, nullptr, nullptr, nullptr, nullptr, nullptr);
        k_bn2<<<1, 128, 0, stream>>>(stat2, g2, be2, sc2, sh2);
        k_main<2><<<2048, 256, 0, stream>>>(y, node_deg, A3, cvec, W1, E64b, stat2,
                                            nullptr, sc2, sh2, W2, b2, out);
    }
}

// Round 5
// 519.146 us; speedup vs baseline: 3.0520x; 1.2980x over previous
//
#include <hip/hip_runtime.h>

#define N_NODES 262144
#define N_EDGES 8388608
#define EPB 8192
#define NBLK (N_EDGES / EPB)
#define NBKT 1024

typedef unsigned int uint32;
typedef unsigned short ushort16;
typedef __attribute__((ext_vector_type(8))) short short8v;
typedef __attribute__((ext_vector_type(4))) float f32x4;

__device__ __forceinline__ float bf2f(uint32 u) { return __uint_as_float(u << 16); }
__device__ __forceinline__ ushort16 f2bf(float x) {
    uint32 u = __float_as_uint(x);
    u = (u + 0x7fffu + ((u >> 16) & 1u)) >> 16;
    return (ushort16)u;
}
__device__ __forceinline__ float lrelu(float v) { return v > 0.f ? v : 0.01f * v; }

// ---------------- binning scatter (zero global atomics) ----------------
__global__ __launch_bounds__(256) void k_hist(const int* __restrict__ ei,
                                              uint32* __restrict__ counts) {
    __shared__ uint32 cnt[NBKT];
    int t = threadIdx.x;
    for (int j = t; j < NBKT; j += 256) cnt[j] = 0;
    __syncthreads();
    int base = blockIdx.x * EPB;
    for (int ch = 0; ch < EPB / 256; ++ch) {
        int d = ei[N_EDGES + base + ch * 256 + t];
        atomicAdd(&cnt[d >> 8], 1u);
    }
    __syncthreads();
    for (int j = t; j < NBKT; j += 256) counts[blockIdx.x * NBKT + j] = cnt[j];
}

__global__ __launch_bounds__(256) void k_scanB(const uint32* __restrict__ counts,
                                               uint32* __restrict__ offsL,
                                               uint32* __restrict__ btot) {
    int b = blockIdx.x, t = threadIdx.x;
    uint32 a[4], s = 0;
    #pragma unroll
    for (int j = 0; j < 4; ++j) { a[j] = counts[(4 * t + j) * NBKT + b]; s += a[j]; }
    int lane = t & 63, wid = t >> 6;
    uint32 v = s;
    #pragma unroll
    for (int o = 1; o < 64; o <<= 1) {
        uint32 u = __shfl_up(v, o, 64);
        if (lane >= o) v += u;
    }
    __shared__ uint32 wt[4];
    if (lane == 63) wt[wid] = v;
    __syncthreads();
    uint32 wbase = 0;
    for (int w = 0; w < wid; ++w) wbase += wt[w];
    uint32 run = wbase + v - s;
    #pragma unroll
    for (int j = 0; j < 4; ++j) { offsL[(4 * t + j) * NBKT + b] = run; run += a[j]; }
    if (t == 255) btot[b] = run;
}

__global__ __launch_bounds__(256) void k_scanTot(const uint32* __restrict__ btot,
                                                 uint32* __restrict__ bstart) {
    int t = threadIdx.x;
    uint32 c[4], s = 0;
    #pragma unroll
    for (int j = 0; j < 4; ++j) { c[j] = btot[t * 4 + j]; s += c[j]; }
    int lane = t & 63, wid = t >> 6;
    uint32 v = s;
    #pragma unroll
    for (int o = 1; o < 64; o <<= 1) {
        uint32 u = __shfl_up(v, o, 64);
        if (lane >= o) v += u;
    }
    __shared__ uint32 wt[4];
    if (lane == 63) wt[wid] = v;
    __syncthreads();
    uint32 wbase = 0;
    for (int w = 0; w < wid; ++w) wbase += wt[w];
    uint32 run = wbase + v - s;
    #pragma unroll
    for (int j = 0; j < 4; ++j) { bstart[t * 4 + j] = run; run += c[j]; }
}

__global__ __launch_bounds__(256) void k_bin(const int* __restrict__ ei,
                                             const uint32* __restrict__ offsL,
                                             const uint32* __restrict__ bstart,
                                             uint32* __restrict__ binned) {
    __shared__ uint32 cnt[NBKT];
    __shared__ uint32 base[NBKT];
    int t = threadIdx.x;
    for (int j = t; j < NBKT; j += 256) {
        cnt[j] = 0;
        base[j] = bstart[j] + offsL[blockIdx.x * NBKT + j];
    }
    __syncthreads();
    int eb = blockIdx.x * EPB;
    for (int ch = 0; ch < EPB / 256; ++ch) {
        int e = eb + ch * 256 + t;
        uint32 s = (uint32)ei[e];
        uint32 d = (uint32)ei[N_EDGES + e];
        uint32 b = d >> 8;
        uint32 r = atomicAdd(&cnt[b], 1u);
        binned[base[b] + r] = (s << 8) | (d & 255u);
    }
}

__global__ __launch_bounds__(256) void k_accum(const uint32* __restrict__ binned,
                                               const uint32* __restrict__ bstart,
                                               const uint32* __restrict__ btot,
                                               const float* __restrict__ pos,
                                               float* __restrict__ agg) {
    __shared__ float acc[768];
    int t = threadIdx.x;
    acc[t] = 0.f; acc[256 + t] = 0.f; acc[512 + t] = 0.f;
    __syncthreads();
    int b = blockIdx.x;
    uint32 st = bstart[b], ct = btot[b];
    for (uint32 i = t; i < ct; i += 256) {
        uint32 w = binned[st + i];
        uint32 s = w >> 8, dl = w & 255u;
        const float* p = pos + 3 * s;
        float p0 = p[0], p1 = p[1], p2 = p[2];
        atomicAdd(&acc[dl * 3 + 0], p0);
        atomicAdd(&acc[dl * 3 + 1], p1);
        atomicAdd(&acc[dl * 3 + 2], p2);
    }
    __syncthreads();
    float* o = agg + (size_t)b * 768;
    o[t] = acc[t]; o[256 + t] = acc[256 + t]; o[512 + t] = acc[512 + t];
}

// fallback: plain atomic scatter (used only if workspace is too small)
__global__ __launch_bounds__(256) void k_scatter(const int* __restrict__ ei,
                                                 const float* __restrict__ pos,
                                                 float* __restrict__ agg) {
    int e = blockIdx.x * 256 + threadIdx.x;
    int s = ei[e];
    int d = ei[N_EDGES + e];
    const float* p = pos + 3 * s;
    float* a = agg + 3 * d;
    atomicAdd(a + 0, p[0]);
    atomicAdd(a + 1, p[1]);
    atomicAdd(a + 2, p[2]);
}

// K2: y = (1+eps)*pos + agg; accumulate 9 moments of y (analytic BN1)
__global__ __launch_bounds__(256) void k_y_moments(const float* __restrict__ pos,
                                                   const float* __restrict__ agg,
                                                   const float* __restrict__ epsp,
                                                   float* __restrict__ y,
                                                   float* __restrict__ mom) {
    int n = blockIdx.x * 256 + threadIdx.x;
    float e1 = 1.f + epsp[0];
    float y0 = e1 * pos[3 * n + 0] + agg[3 * n + 0];
    float y1 = e1 * pos[3 * n + 1] + agg[3 * n + 1];
    float y2 = e1 * pos[3 * n + 2] + agg[3 * n + 2];
    y[3 * n + 0] = y0; y[3 * n + 1] = y1; y[3 * n + 2] = y2;
    float m[9] = {y0, y1, y2, y0 * y0, y0 * y1, y0 * y2, y1 * y1, y1 * y2, y2 * y2};
    #pragma unroll
    for (int j = 0; j < 9; ++j) {
        #pragma unroll
        for (int o = 1; o < 64; o <<= 1) m[j] += __shfl_xor(m[j], o, 64);
    }
    __shared__ float buf[4][9];
    int lane = threadIdx.x & 63, wid = threadIdx.x >> 6;
    if (lane == 0) {
        #pragma unroll
        for (int j = 0; j < 9; ++j) buf[wid][j] = m[j];
    }
    __syncthreads();
    if (threadIdx.x < 9) {
        float s = buf[0][threadIdx.x] + buf[1][threadIdx.x] + buf[2][threadIdx.x] + buf[3][threadIdx.x];
        atomicAdd(&mom[threadIdx.x], s);
    }
}

// K3a: analytic BN1 -> fold BN+affine into A3 (3x128) and cvec (128)
__global__ __launch_bounds__(128) void k_bn1(const float* __restrict__ mom,
                                             const float* __restrict__ Wc,
                                             const float* __restrict__ bc,
                                             const float* __restrict__ g1,
                                             const float* __restrict__ be1,
                                             float* __restrict__ A3,
                                             float* __restrict__ cvec) {
    int d = threadIdx.x;
    float inv = 1.f / (float)N_NODES;
    float m0 = mom[0] * inv, m1 = mom[1] * inv, m2 = mom[2] * inv;
    float c00 = mom[3] * inv - m0 * m0;
    float c01 = mom[4] * inv - m0 * m1;
    float c02 = mom[5] * inv - m0 * m2;
    float c11 = mom[6] * inv - m1 * m1;
    float c12 = mom[7] * inv - m1 * m2;
    float c22 = mom[8] * inv - m2 * m2;
    float w0 = Wc[d], w1 = Wc[128 + d], w2 = Wc[256 + d];
    float mu = m0 * w0 + m1 * w1 + m2 * w2 + bc[d];
    float var = c00 * w0 * w0 + c11 * w1 * w1 + c22 * w2 * w2 +
                2.f * (c01 * w0 * w1 + c02 * w0 * w2 + c12 * w1 * w2);
    float s1 = g1[d] * rsqrtf(var + 1e-5f);
    float sh1 = be1[d] - mu * s1;
    A3[d] = w0 * s1;
    A3[128 + d] = w1 * s1;
    A3[256 + d] = w2 * s1;
    cvec[d] = bc[d] * s1 + sh1;
}

// K3b: E64b[c][d] = b1[d] + embed[c] @ W1_top  (embedding branch -> 64x128 LUT)
__global__ __launch_bounds__(128) void k_e64(const float* __restrict__ emb,
                                             const float* __restrict__ W1,
                                             const float* __restrict__ b1,
                                             float* __restrict__ E64b) {
    int c = blockIdx.x, d = threadIdx.x;
    float acc = b1[d];
    for (int k = 0; k < 128; ++k) acc += emb[c * 128 + k] * W1[k * 128 + d];
    E64b[c * 128 + d] = acc;
}

// ---------------- MFMA main pass ----------------
// Per block: 128 nodes. x=lrelu(y@A3+cvec) bf16 frag-packed LDS; W1bot bf16
// frag-packed LDS; 4 waves x (2 M x 8 N frags) x mfma_f32_16x16x32_bf16.
// Epilogue: acc->H (pitch 132), +E64b[deg], bf16 h store, per-feature
// sum/sumsq partials (PLAIN stores into the dead agg region — round-4
// lesson: partial must NOT alias hbuf; both are written by this kernel).
__global__ __launch_bounds__(256, 2) void k_gemm_mfma(const float* __restrict__ y,
                                                      const int* __restrict__ deg,
                                                      const float* __restrict__ A3,
                                                      const float* __restrict__ cvec,
                                                      const float* __restrict__ W1,
                                                      const float* __restrict__ E64b,
                                                      float* __restrict__ partial,
                                                      ushort16* __restrict__ hout) {
    __shared__ __align__(16) char Lraw[128 * 132 * 4];  // 67.6 KB, overlaid
    __shared__ float red[512];
    short* Wl = (short*)Lraw;             // [16384] bf16, frag-packed
    short* Xl = (short*)(Lraw + 32768);   // [16384] bf16, frag-packed
    float* H  = (float*)Lraw;             // [128][132] fp32 h tile

    const int t = threadIdx.x;
    const int nbase = blockIdx.x * 128;

    // stage W1bot -> Wl (idx = ((nf*4+s)*4+kg)*128 + n16*8 + j)
    {
        int n = t & 127, kh = t >> 7;
        int nf = n >> 4, n16 = n & 15;
        #pragma unroll
        for (int q = 0; q < 8; ++q) {
            int kb = kh * 64 + q * 8;
            short pk[8];
            #pragma unroll
            for (int j = 0; j < 8; ++j)
                pk[j] = (short)f2bf(W1[(128 + kb + j) * 128 + n]);
            int s = kb >> 5, kg = (kb >> 3) & 3;
            *(short8v*)&Wl[(((nf * 4 + s) * 4 + kg) * 16 + n16) * 8] = *(short8v*)pk;
        }
    }
    // stage x -> Xl (idx = ((mf*4+s)*4+kg)*128 + m16*8 + j)
    {
        int k8 = t & 15, mg = t >> 4;
        f32x4 aA0 = *(const f32x4*)&A3[k8 * 8],       aA1 = *(const f32x4*)&A3[k8 * 8 + 4];
        f32x4 aB0 = *(const f32x4*)&A3[128 + k8 * 8], aB1 = *(const f32x4*)&A3[128 + k8 * 8 + 4];
        f32x4 aC0 = *(const f32x4*)&A3[256 + k8 * 8], aC1 = *(const f32x4*)&A3[256 + k8 * 8 + 4];
        f32x4 cv0 = *(const f32x4*)&cvec[k8 * 8],     cv1 = *(const f32x4*)&cvec[k8 * 8 + 4];
        int s = k8 >> 2, kg = k8 & 3;
        #pragma unroll
        for (int mm = 0; mm < 8; ++mm) {
            int m = mg * 8 + mm;
            const float* yy = y + (size_t)(nbase + m) * 3;
            float y0 = yy[0], y1 = yy[1], y2 = yy[2];
            short pk[8];
            #pragma unroll
            for (int j = 0; j < 4; ++j) {
                pk[j]     = (short)f2bf(lrelu(y0 * aA0[j] + y1 * aB0[j] + y2 * aC0[j] + cv0[j]));
                pk[4 + j] = (short)f2bf(lrelu(y0 * aA1[j] + y1 * aB1[j] + y2 * aC1[j] + cv1[j]));
            }
            *(short8v*)&Xl[(((m >> 4) * 4 + s) * 4 + kg) * 16 * 8 + (m & 15) * 8] = *(short8v*)pk;
        }
    }
    __syncthreads();

    // MFMA GEMM
    const int w = t >> 6, l = t & 63;
    const int lk = l >> 4, l16 = l & 15;
    f32x4 acc[2][8];
    #pragma unroll
    for (int a = 0; a < 2; ++a)
        #pragma unroll
        for (int b = 0; b < 8; ++b) acc[a][b] = (f32x4)(0.f);
    #pragma unroll
    for (int s = 0; s < 4; ++s) {
        short8v af[2], bf[8];
        #pragma unroll
        for (int mf2 = 0; mf2 < 2; ++mf2) {
            int mf = w * 2 + mf2;
            af[mf2] = *(short8v*)&Xl[(((mf * 4 + s) * 4 + lk) * 16 + l16) * 8];
        }
        #pragma unroll
        for (int nf = 0; nf < 8; ++nf)
            bf[nf] = *(short8v*)&Wl[(((nf * 4 + s) * 4 + lk) * 16 + l16) * 8];
        #pragma unroll
        for (int mf2 = 0; mf2 < 2; ++mf2)
            #pragma unroll
            for (int nf = 0; nf < 8; ++nf)
                acc[mf2][nf] = __builtin_amdgcn_mfma_f32_16x16x32_bf16(af[mf2], bf[nf], acc[mf2][nf], 0, 0, 0);
    }
    __syncthreads();  // Xl/Wl dead; H takes over

    // acc -> H
    #pragma unroll
    for (int mf2 = 0; mf2 < 2; ++mf2) {
        int rbase = (w * 2 + mf2) * 16 + lk * 4;
        #pragma unroll
        for (int nf = 0; nf < 8; ++nf) {
            int c = nf * 16 + l16;
            #pragma unroll
            for (int r = 0; r < 4; ++r)
                H[(rbase + r) * 132 + c] = acc[mf2][nf][r];
        }
    }
    __syncthreads();

    // row pass: += E64b[deg], store bf16 h, write back to H for stats
    {
        int m = t >> 1, ch = (t & 1) * 64;
        int node = nbase + m;
        int dg = deg[node];
        const float* Er = E64b + (size_t)dg * 128 + ch;
        #pragma unroll
        for (int q = 0; q < 8; ++q) {
            int c = ch + q * 8;
            f32x4 h0 = *(f32x4*)&H[m * 132 + c];
            f32x4 h1 = *(f32x4*)&H[m * 132 + c + 4];
            f32x4 e0 = *(const f32x4*)&Er[q * 8];
            f32x4 e1 = *(const f32x4*)&Er[q * 8 + 4];
            h0 += e0; h1 += e1;
            *(f32x4*)&H[m * 132 + c] = h0;
            *(f32x4*)&H[m * 132 + c + 4] = h1;
            uint32 pk[4];
            #pragma unroll
            for (int j = 0; j < 4; ++j) {
                float lo = (j < 2) ? h0[2 * j] : h1[2 * (j - 2)];
                float hi = (j < 2) ? h0[2 * j + 1] : h1[2 * (j - 2) + 1];
                pk[j] = (uint32)f2bf(lo) | ((uint32)f2bf(hi) << 16);
            }
            *(uint4*)&hout[(size_t)node * 128 + c] = *(uint4*)pk;
        }
    }
    __syncthreads();

    // col pass: per-feature sum/sumsq over the 128-node tile
    {
        int c2 = t & 127, nh = t >> 7;
        float ps = 0.f, pq = 0.f;
        #pragma unroll 8
        for (int i = 0; i < 64; ++i) {
            float v = H[(nh * 64 + i) * 132 + c2];
            ps += v; pq += v * v;
        }
        red[t] = ps; red[256 + t] = pq;
    }
    __syncthreads();
    if (t < 128) {
        float S = red[t] + red[t + 128];
        float Q = red[256 + t] + red[256 + t + 128];
        partial[(size_t)blockIdx.x * 256 + t] = S;
        partial[(size_t)blockIdx.x * 256 + 128 + t] = Q;
    }
}

// sum per-block partials -> stat2 (few atomics)
__global__ __launch_bounds__(256) void k_red(const float* __restrict__ partial,
                                             float* __restrict__ stat2) {
    int t = threadIdx.x;
    float s = 0.f;
    int rb = blockIdx.x * 64;
    for (int r = 0; r < 64; ++r) s += partial[(size_t)(rb + r) * 256 + t];
    atomicAdd(&stat2[t], s);
}

// fallback VALU k_main (MODE 1: stats only; MODE 2: final output)
template <int MODE>
__global__ __launch_bounds__(256, 2) void k_main(const float* __restrict__ y,
                                                 const int* __restrict__ deg,
                                                 const float* __restrict__ A3,
                                                 const float* __restrict__ cvec,
                                                 const float* __restrict__ W1,
                                                 const float* __restrict__ E64b,
                                                 float* __restrict__ stat2,
                                                 const float* __restrict__ sc2,
                                                 const float* __restrict__ sh2,
                                                 const float* __restrict__ W2,
                                                 const float* __restrict__ b2,
                                                 float* __restrict__ out) {
    __shared__ float Wl[128][128];
    __shared__ float xl[32][128];
    for (int i = threadIdx.x; i < 128 * 128; i += 256)
        Wl[i >> 7][i & 127] = W1[16384 + i];
    const int fg = threadIdx.x & 15;
    const int np = threadIdx.x >> 4;
    const int f0 = fg * 8;
    const int n0 = np * 2;
    const int fx = threadIdx.x & 127;
    const int nb = threadIdx.x >> 7;
    float a0 = A3[fx], a1 = A3[128 + fx], a2 = A3[256 + fx], cv = cvec[fx];
    float ssum[8] = {0}, ssq[8] = {0};
    float s2v[8], t2v[8], w2v[8], b2v = 0.f;
    if constexpr (MODE == 2) {
        *(float4*)&s2v[0] = *(const float4*)&sc2[f0];
        *(float4*)&s2v[4] = *(const float4*)&sc2[f0 + 4];
        *(float4*)&t2v[0] = *(const float4*)&sh2[f0];
        *(float4*)&t2v[4] = *(const float4*)&sh2[f0 + 4];
        *(float4*)&w2v[0] = *(const float4*)&W2[f0];
        *(float4*)&w2v[4] = *(const float4*)&W2[f0 + 4];
        b2v = b2[0];
    }
    for (int it = 0; it < 4; ++it) {
        int nbase = (blockIdx.x * 4 + it) * 32;
        __syncthreads();
        #pragma unroll
        for (int s = 0; s < 16; ++s) {
            int n = nb + s * 2;
            const float* yy = y + (nbase + n) * 3;
            float v = yy[0] * a0 + yy[1] * a1 + yy[2] * a2 + cv;
            xl[n][fx] = lrelu(v);
        }
        __syncthreads();
        float acc0[8] = {0}, acc1[8] = {0};
        for (int k4 = 0; k4 < 32; ++k4) {
            float xs0[4], xs1[4];
            *(float4*)xs0 = *(const float4*)&xl[n0][k4 * 4];
            *(float4*)xs1 = *(const float4*)&xl[n0 + 1][k4 * 4];
            #pragma unroll
            for (int kk = 0; kk < 4; ++kk) {
                float4 wA = *(const float4*)&Wl[k4 * 4 + kk][f0];
                float4 wB = *(const float4*)&Wl[k4 * 4 + kk][f0 + 4];
                float xa = xs0[kk], xb = xs1[kk];
                acc0[0] += xa * wA.x; acc0[1] += xa * wA.y; acc0[2] += xa * wA.z; acc0[3] += xa * wA.w;
                acc0[4] += xa * wB.x; acc0[5] += xa * wB.y; acc0[6] += xa * wB.z; acc0[7] += xa * wB.w;
                acc1[0] += xb * wA.x; acc1[1] += xb * wA.y; acc1[2] += xb * wA.z; acc1[3] += xb * wA.w;
                acc1[4] += xb * wB.x; acc1[5] += xb * wB.y; acc1[6] += xb * wB.z; acc1[7] += xb * wB.w;
            }
        }
        int nA = nbase + n0, nB = nA + 1;
        int dA = deg[nA], dB = deg[nB];
        float eA[8], eB[8], hA[8], hB[8];
        *(float4*)&eA[0] = *(const float4*)&E64b[dA * 128 + f0];
        *(float4*)&eA[4] = *(const float4*)&E64b[dA * 128 + f0 + 4];
        *(float4*)&eB[0] = *(const float4*)&E64b[dB * 128 + f0];
        *(float4*)&eB[4] = *(const float4*)&E64b[dB * 128 + f0 + 4];
        #pragma unroll
        for (int j = 0; j < 8; ++j) { hA[j] = acc0[j] + eA[j]; hB[j] = acc1[j] + eB[j]; }
        if constexpr (MODE == 1) {
            #pragma unroll
            for (int j = 0; j < 8; ++j) {
                ssum[j] += hA[j] + hB[j];
                ssq[j] += hA[j] * hA[j] + hB[j] * hB[j];
            }
        }
        if constexpr (MODE == 2) {
            float pA = 0.f, pB = 0.f;
            #pragma unroll
            for (int j = 0; j < 8; ++j) {
                pA += lrelu(hA[j] * s2v[j] + t2v[j]) * w2v[j];
                pB += lrelu(hB[j] * s2v[j] + t2v[j]) * w2v[j];
            }
            #pragma unroll
            for (int o = 1; o < 16; o <<= 1) {
                pA += __shfl_xor(pA, o, 64);
                pB += __shfl_xor(pB, o, 64);
            }
            if (fg == 0) {
                out[nA] = 1.f / (1.f + expf(-(pA + b2v)));
                out[nB] = 1.f / (1.f + expf(-(pB + b2v)));
            }
        }
    }
    if constexpr (MODE == 1) {
        __syncthreads();
        #pragma unroll
        for (int j = 0; j < 8; ++j) {
            ssum[j] += __shfl_xor(ssum[j], 16, 64);
            ssum[j] += __shfl_xor(ssum[j], 32, 64);
            ssq[j] += __shfl_xor(ssq[j], 16, 64);
            ssq[j] += __shfl_xor(ssq[j], 32, 64);
        }
        float* redp = &xl[0][0];
        int lane = threadIdx.x & 63, wid = threadIdx.x >> 6;
        if (lane < 16) {
            #pragma unroll
            for (int j = 0; j < 8; ++j) {
                redp[wid * 256 + lane * 16 + j] = ssum[j];
                redp[wid * 256 + lane * 16 + 8 + j] = ssq[j];
            }
        }
        __syncthreads();
        if (threadIdx.x < 128) {
            int d = threadIdx.x, fgg = d >> 3, j = d & 7;
            float s = redp[fgg * 16 + j] + redp[256 + fgg * 16 + j] +
                      redp[512 + fgg * 16 + j] + redp[768 + fgg * 16 + j];
            float q = redp[fgg * 16 + 8 + j] + redp[256 + fgg * 16 + 8 + j] +
                      redp[512 + fgg * 16 + 8 + j] + redp[768 + fgg * 16 + 8 + j];
            atomicAdd(&stat2[d], s);
            atomicAdd(&stat2[128 + d], q);
        }
    }
}

// K5: finalize BN2 scale/shift from stats
__global__ __launch_bounds__(128) void k_bn2(const float* __restrict__ stat2,
                                             const float* __restrict__ g2,
                                             const float* __restrict__ be2,
                                             float* __restrict__ sc2,
                                             float* __restrict__ sh2) {
    int d = threadIdx.x;
    float inv = 1.f / (float)N_NODES;
    float mu = stat2[d] * inv;
    float var = stat2[128 + d] * inv - mu * mu;
    float s = g2[d] * rsqrtf(var + 1e-5f);
    sc2[d] = s;
    sh2[d] = be2[d] - mu * s;
}

// K6: final elementwise from stored bf16 h
__global__ __launch_bounds__(256) void k_final_h(const ushort16* __restrict__ h,
                                                 const float* __restrict__ sc2,
                                                 const float* __restrict__ sh2,
                                                 const float* __restrict__ W2,
                                                 const float* __restrict__ b2,
                                                 float* __restrict__ out) {
    int t = blockIdx.x * 256 + threadIdx.x;
    int node = t >> 3, part = t & 7;
    const ushort16* hp = h + (size_t)node * 128 + part * 16;
    uint32 ua[4], ub[4];
    *(uint4*)ua = *(const uint4*)hp;
    *(uint4*)ub = *(const uint4*)(hp + 8);
    int fb = part * 16;
    float pd = 0.f;
    #pragma unroll
    for (int q = 0; q < 4; ++q) {
        int f = fb + 2 * q;
        float v0 = bf2f(ua[q] & 0xffffu), v1 = bf2f(ua[q] >> 16);
        pd += lrelu(v0 * sc2[f] + sh2[f]) * W2[f];
        pd += lrelu(v1 * sc2[f + 1] + sh2[f + 1]) * W2[f + 1];
        int g = fb + 8 + 2 * q;
        float w0 = bf2f(ub[q] & 0xffffu), w1 = bf2f(ub[q] >> 16);
        pd += lrelu(w0 * sc2[g] + sh2[g]) * W2[g];
        pd += lrelu(w1 * sc2[g + 1] + sh2[g + 1]) * W2[g + 1];
    }
    pd += __shfl_xor(pd, 1, 64);
    pd += __shfl_xor(pd, 2, 64);
    pd += __shfl_xor(pd, 4, 64);
    if (part == 0) out[node] = 1.f / (1.f + expf(-(pd + b2[0])));
}

extern "C" void kernel_launch(void* const* d_in, const int* in_sizes, int n_in,
                              void* d_out, int out_size, void* d_ws, size_t ws_size,
                              hipStream_t stream) {
    const int*   node_deg = (const int*)d_in[0];
    const int*   ei       = (const int*)d_in[1];
    const float* pos      = (const float*)d_in[2];
    const float* emb      = (const float*)d_in[3];
    const float* epsp     = (const float*)d_in[4];
    const float* Wc       = (const float*)d_in[5];
    const float* bc       = (const float*)d_in[6];
    const float* g1       = (const float*)d_in[7];
    const float* be1      = (const float*)d_in[8];
    const float* W1       = (const float*)d_in[9];
    const float* b1       = (const float*)d_in[10];
    const float* g2       = (const float*)d_in[11];
    const float* be2      = (const float*)d_in[12];
    const float* W2       = (const float*)d_in[13];
    const float* b2       = (const float*)d_in[14];
    float* out = (float*)d_out;

    float* F = (float*)d_ws;
    float* agg    = F;                    // 786432 (dead after k_y_moments)
    float* y      = F + 786432;           // 786432
    float* mom    = F + 1572864;          // 16
    float* stat2  = F + 1572880;          // 256
    float* A3     = F + 1573136;          // 384
    float* cvec   = F + 1573520;          // 128
    float* E64b   = F + 1573648;          // 8192
    float* sc2    = F + 1581840;          // 128
    float* sh2    = F + 1581968;          // 128
    uint32* bstart = (uint32*)(F + 1582096);  // 1024
    uint32* btot   = (uint32*)(F + 1583120);  // 1024
    float* U      = F + 1584144;          // overlay region
    uint32* binned = (uint32*)U;                 // 8388608 u32 (33.5 MB)
    uint32* counts = (uint32*)(U + 8388608);     // 1048576 u32
    uint32* offsL  = (uint32*)(U + 9437184);     // 1048576 u32
    ushort16* hbuf = (ushort16*)U;               // 64 MB, aliases binned+counts+offsL
    // partial aliases agg (dead after k_y_moments) — must NOT live inside
    // hbuf: k_gemm_mfma writes hbuf and partial concurrently (round-4 NaN).
    float* partial = agg;                        // 524288 f32 needed, 786432 avail

    const size_t needBinH  = (size_t)(1584144 + 16777216) * 4;
    const size_t needBin   = (size_t)(1584144 + 10485760) * 4;
    bool useBin, storeH;
    if      (ws_size >= needBinH) { useBin = true;  storeH = true;  }
    else if (ws_size >= needBin)  { useBin = true;  storeH = false; }
    else                          { useBin = false; storeH = false; }

    hipMemsetAsync(mom, 0, 272 * 4, stream);  // mom + stat2 contiguous

    if (useBin) {
        k_hist<<<NBLK, 256, 0, stream>>>(ei, counts);
        k_scanB<<<NBKT, 256, 0, stream>>>(counts, offsL, btot);
        k_scanTot<<<1, 256, 0, stream>>>(btot, bstart);
        k_bin<<<NBLK, 256, 0, stream>>>(ei, offsL, bstart, binned);
        k_accum<<<NBKT, 256, 0, stream>>>(binned, bstart, btot, pos, agg);
    } else {
        hipMemsetAsync(agg, 0, 786432 * 4, stream);
        k_scatter<<<N_EDGES / 256, 256, 0, stream>>>(ei, pos, agg);
    }
    k_y_moments<<<N_NODES / 256, 256, 0, stream>>>(pos, agg, epsp, y, mom);
    k_bn1<<<1, 128, 0, stream>>>(mom, Wc, bc, g1, be1, A3, cvec);
    k_e64<<<64, 128, 0, stream>>>(emb, W1, b1, E64b);

    if (storeH) {
        k_gemm_mfma<<<N_NODES / 128, 256, 0, stream>>>(y, node_deg, A3, cvec, W1,
                                                       E64b, partial, hbuf);
        k_red<<<32, 256, 0, stream>>>(partial, stat2);
        k_bn2<<<1, 128, 0, stream>>>(stat2, g2, be2, sc2, sh2);
        k_final_h<<<N_NODES / 32, 256, 0, stream>>>(hbuf, sc2, sh2, W2, b2, out);
    } else {
        k_main<1><<<2048, 256, 0, stream>>>(y, node_deg, A3, cvec, W1, E64b, stat2,
                                            nullptr, nullptr, nullptr, nullptr, nullptr);
        k_bn2<<<1, 128, 0, stream>>>(stat2, g2, be2, sc2, sh2);
        k_main<2><<<2048, 256, 0, stream>>>(y, node_deg, A3, cvec, W1, E64b, stat2,
                                            sc2, sh2, W2, b2, out);
    }
}

// Round 10
// 431.441 us; speedup vs baseline: 3.6724x; 1.2033x over previous
//
#include <hip/hip_runtime.h>

#define N_NODES 262144
#define N_EDGES 8388608
#define EPB 8192
#define NBLK (N_EDGES / EPB)   // 1024 binning blocks
#define NBKT 256               // buckets of 1024 nodes (N = 256*1024)
#define BSH 10                 // bucket = dst >> BSH
#define ACC_SPLIT 4

typedef unsigned int uint32;
typedef unsigned short ushort16;
typedef unsigned char uchar8;
typedef __attribute__((ext_vector_type(8))) short short8v;
typedef __attribute__((ext_vector_type(4))) float f32x4;

__device__ __forceinline__ float bf2f(uint32 u) { return __uint_as_float(u << 16); }
__device__ __forceinline__ ushort16 f2bf(float x) {
    uint32 u = __float_as_uint(x);
    u = (u + 0x7fffu + ((u >> 16) & 1u)) >> 16;
    return (ushort16)u;
}
__device__ __forceinline__ float lrelu(float v) { return v > 0.f ? v : 0.01f * v; }

// ---------------- binning scatter (zero global atomics) ----------------
// A: per-block histogram of dst buckets
__global__ __launch_bounds__(256) void k_hist(const int* __restrict__ ei,
                                              uint32* __restrict__ counts) {
    __shared__ uint32 cnt[NBKT];
    int t = threadIdx.x;
    cnt[t] = 0;
    __syncthreads();
    int base = blockIdx.x * EPB;
    for (int ch = 0; ch < EPB / 256; ++ch) {
        int d = ei[N_EDGES + base + ch * 256 + t];
        atomicAdd(&cnt[d >> BSH], 1u);
    }
    __syncthreads();
    counts[blockIdx.x * NBKT + t] = cnt[t];
}

// B1: per-bucket exclusive scan over the 1024 block counts -> offsL, btot
__global__ __launch_bounds__(256) void k_scanB(const uint32* __restrict__ counts,
                                               uint32* __restrict__ offsL,
                                               uint32* __restrict__ btot) {
    int b = blockIdx.x, t = threadIdx.x;
    uint32 a[4], s = 0;
    #pragma unroll
    for (int j = 0; j < 4; ++j) { a[j] = counts[(4 * t + j) * NBKT + b]; s += a[j]; }
    int lane = t & 63, wid = t >> 6;
    uint32 v = s;
    #pragma unroll
    for (int o = 1; o < 64; o <<= 1) {
        uint32 u = __shfl_up(v, o, 64);
        if (lane >= o) v += u;
    }
    __shared__ uint32 wt[4];
    if (lane == 63) wt[wid] = v;
    __syncthreads();
    uint32 wbase = 0;
    for (int w = 0; w < wid; ++w) wbase += wt[w];
    uint32 run = wbase + v - s;
    #pragma unroll
    for (int j = 0; j < 4; ++j) { offsL[(4 * t + j) * NBKT + b] = run; run += a[j]; }
    if (t == 255) btot[b] = run;
}

// B2: exclusive scan of 256 bucket totals -> bucket start offsets
__global__ __launch_bounds__(256) void k_scanTot(const uint32* __restrict__ btot,
                                                 uint32* __restrict__ bstart) {
    int t = threadIdx.x;
    uint32 v = btot[t];
    uint32 inc = v;
    int lane = t & 63, wid = t >> 6;
    #pragma unroll
    for (int o = 1; o < 64; o <<= 1) {
        uint32 u = __shfl_up(inc, o, 64);
        if (lane >= o) inc += u;
    }
    __shared__ uint32 wt[4];
    if (lane == 63) wt[wid] = inc;
    __syncthreads();
    uint32 wbase = 0;
    for (int w = 0; w < wid; ++w) wbase += wt[w];
    bstart[t] = wbase + inc - v;
}

// C: in-LDS counting sort, then COALESCED bucket-run writes.
// Round-5 lesson: scattered per-lane 4B stores = 64 fabric txns/wave and 6x
// write amplification (208 MB for a 33.5 MB payload). Sorting the block's
// 8192 payloads in LDS first makes consecutive lanes write consecutive
// addresses within each bucket run (avg 32 edges = 128 B).
__global__ __launch_bounds__(256) void k_bin(const int* __restrict__ ei,
                                             const uint32* __restrict__ offsL,
                                             const uint32* __restrict__ bstart,
                                             uint32* __restrict__ binned) {
    __shared__ uint32 pay[EPB];        // 32 KB
    __shared__ uchar8 bkt[EPB];        // 8 KB
    __shared__ uint32 cnt[NBKT];
    __shared__ uint32 lstart[NBKT];
    __shared__ uint32 cursor[NBKT];
    __shared__ uint32 gbase[NBKT];
    __shared__ uint32 wt[4];
    int t = threadIdx.x;
    cnt[t] = 0;
    gbase[t] = bstart[t] + offsL[blockIdx.x * NBKT + t];
    __syncthreads();
    int eb = blockIdx.x * EPB;
    // pass 1: histogram (dst only)
    for (int ch = 0; ch < EPB / 256; ++ch) {
        int d = ei[N_EDGES + eb + ch * 256 + t];
        atomicAdd(&cnt[d >> BSH], 1u);
    }
    __syncthreads();
    // exclusive scan of cnt[256]
    {
        uint32 v = cnt[t];
        uint32 inc = v;
        int lane = t & 63, wid = t >> 6;
        #pragma unroll
        for (int o = 1; o < 64; o <<= 1) {
            uint32 u = __shfl_up(inc, o, 64);
            if (lane >= o) inc += u;
        }
        if (lane == 63) wt[wid] = inc;
        __syncthreads();
        uint32 wbase = 0;
        for (int w = 0; w < wid; ++w) wbase += wt[w];
        uint32 ex = wbase + inc - v;
        lstart[t] = ex;
        cursor[t] = ex;
    }
    __syncthreads();
    // pass 2: place payloads into LDS-sorted order (edge re-read is L1/L2-hot)
    for (int ch = 0; ch < EPB / 256; ++ch) {
        int e = eb + ch * 256 + t;
        uint32 s = (uint32)ei[e];
        uint32 d = (uint32)ei[N_EDGES + e];
        uint32 b = d >> BSH;
        uint32 p = atomicAdd(&cursor[b], 1u);
        pay[p] = (s << BSH) | (d & ((1u << BSH) - 1u));
        bkt[p] = (uchar8)b;
    }
    __syncthreads();
    // pass 3: linear LDS -> per-bucket-run coalesced global writes
    for (int ch = 0; ch < EPB / 256; ++ch) {
        int p = ch * 256 + t;
        uint32 b = bkt[p];
        binned[gbase[b] + (uint32)p - lstart[b]] = pay[p];
    }
}

// D: per (bucket, split) LDS accumulation; exclusive partial-slice writes
__global__ __launch_bounds__(256) void k_accum(const uint32* __restrict__ binned,
                                               const uint32* __restrict__ bstart,
                                               const uint32* __restrict__ btot,
                                               const float* __restrict__ pos,
                                               float* __restrict__ partialAgg) {
    __shared__ float acc[3072];   // 1024 nodes x 3
    int t = threadIdx.x;
    for (int i = t; i < 3072; i += 256) acc[i] = 0.f;
    __syncthreads();
    int b = blockIdx.x >> 2;
    int q = blockIdx.x & 3;
    uint32 st = bstart[b], ct = btot[b];
    uint32 lo = st + (uint32)(((unsigned long long)ct * q) >> 2);
    uint32 hi = st + (uint32)(((unsigned long long)ct * (q + 1)) >> 2);
    for (uint32 i = lo + t; i < hi; i += 256) {
        uint32 w = binned[i];
        uint32 s = w >> BSH, dl = w & ((1u << BSH) - 1u);
        const float* p = pos + 3 * s;
        float p0 = p[0], p1 = p[1], p2 = p[2];
        atomicAdd(&acc[dl * 3 + 0], p0);
        atomicAdd(&acc[dl * 3 + 1], p1);
        atomicAdd(&acc[dl * 3 + 2], p2);
    }
    __syncthreads();
    float* o = partialAgg + (size_t)blockIdx.x * 3072;
    for (int i = t; i < 3072; i += 256) o[i] = acc[i];
}

// fallback: plain atomic scatter (used only if workspace is too small)
__global__ __launch_bounds__(256) void k_scatter(const int* __restrict__ ei,
                                                 const float* __restrict__ pos,
                                                 float* __restrict__ agg) {
    int e = blockIdx.x * 256 + threadIdx.x;
    int s = ei[e];
    int d = ei[N_EDGES + e];
    const float* p = pos + 3 * s;
    float* a = agg + 3 * d;
    atomicAdd(a + 0, p[0]);
    atomicAdd(a + 1, p[1]);
    atomicAdd(a + 2, p[2]);
}

// K2: y = (1+eps)*pos + agg; accumulate 9 moments of y (analytic BN1)
// R==4: agg comes as 4 partial slices per bucket (k_accum layout)
template <int R>
__global__ __launch_bounds__(256) void k_y_moments(const float* __restrict__ pos,
                                                   const float* __restrict__ aggP,
                                                   const float* __restrict__ epsp,
                                                   float* __restrict__ y,
                                                   float* __restrict__ mom) {
    int n = blockIdx.x * 256 + threadIdx.x;
    float e1 = 1.f + epsp[0];
    float a0, a1, a2;
    if constexpr (R == 4) {
        size_t base = (size_t)(n >> BSH) * 4 * 3072 + (size_t)(n & ((1 << BSH) - 1)) * 3;
        a0 = a1 = a2 = 0.f;
        #pragma unroll
        for (int q = 0; q < 4; ++q) {
            a0 += aggP[base + (size_t)q * 3072 + 0];
            a1 += aggP[base + (size_t)q * 3072 + 1];
            a2 += aggP[base + (size_t)q * 3072 + 2];
        }
    } else {
        a0 = aggP[3 * n + 0]; a1 = aggP[3 * n + 1]; a2 = aggP[3 * n + 2];
    }
    float y0 = e1 * pos[3 * n + 0] + a0;
    float y1 = e1 * pos[3 * n + 1] + a1;
    float y2 = e1 * pos[3 * n + 2] + a2;
    y[3 * n + 0] = y0; y[3 * n + 1] = y1; y[3 * n + 2] = y2;
    float m[9] = {y0, y1, y2, y0 * y0, y0 * y1, y0 * y2, y1 * y1, y1 * y2, y2 * y2};
    #pragma unroll
    for (int j = 0; j < 9; ++j) {
        #pragma unroll
        for (int o = 1; o < 64; o <<= 1) m[j] += __shfl_xor(m[j], o, 64);
    }
    __shared__ float buf[4][9];
    int lane = threadIdx.x & 63, wid = threadIdx.x >> 6;
    if (lane == 0) {
        #pragma unroll
        for (int j = 0; j < 9; ++j) buf[wid][j] = m[j];
    }
    __syncthreads();
    if (threadIdx.x < 9) {
        float s = buf[0][threadIdx.x] + buf[1][threadIdx.x] + buf[2][threadIdx.x] + buf[3][threadIdx.x];
        atomicAdd(&mom[threadIdx.x], s);
    }
}

// K3a: analytic BN1 -> fold BN+affine into A3 (3x128) and cvec (128)
__global__ __launch_bounds__(128) void k_bn1(const float* __restrict__ mom,
                                             const float* __restrict__ Wc,
                                             const float* __restrict__ bc,
                                             const float* __restrict__ g1,
                                             const float* __restrict__ be1,
                                             float* __restrict__ A3,
                                             float* __restrict__ cvec) {
    int d = threadIdx.x;
    float inv = 1.f / (float)N_NODES;
    float m0 = mom[0] * inv, m1 = mom[1] * inv, m2 = mom[2] * inv;
    float c00 = mom[3] * inv - m0 * m0;
    float c01 = mom[4] * inv - m0 * m1;
    float c02 = mom[5] * inv - m0 * m2;
    float c11 = mom[6] * inv - m1 * m1;
    float c12 = mom[7] * inv - m1 * m2;
    float c22 = mom[8] * inv - m2 * m2;
    float w0 = Wc[d], w1 = Wc[128 + d], w2 = Wc[256 + d];
    float mu = m0 * w0 + m1 * w1 + m2 * w2 + bc[d];
    float var = c00 * w0 * w0 + c11 * w1 * w1 + c22 * w2 * w2 +
                2.f * (c01 * w0 * w1 + c02 * w0 * w2 + c12 * w1 * w2);
    float s1 = g1[d] * rsqrtf(var + 1e-5f);
    float sh1 = be1[d] - mu * s1;
    A3[d] = w0 * s1;
    A3[128 + d] = w1 * s1;
    A3[256 + d] = w2 * s1;
    cvec[d] = bc[d] * s1 + sh1;
}

// K3b: E64b[c][d] = b1[d] + embed[c] @ W1_top
__global__ __launch_bounds__(128) void k_e64(const float* __restrict__ emb,
                                             const float* __restrict__ W1,
                                             const float* __restrict__ b1,
                                             float* __restrict__ E64b) {
    int c = blockIdx.x, d = threadIdx.x;
    float acc = b1[d];
    for (int k = 0; k < 128; ++k) acc += emb[c * 128 + k] * W1[k * 128 + d];
    E64b[c * 128 + d] = acc;
}

// ---------------- MFMA main pass ----------------
__global__ __launch_bounds__(256, 2) void k_gemm_mfma(const float* __restrict__ y,
                                                      const int* __restrict__ deg,
                                                      const float* __restrict__ A3,
                                                      const float* __restrict__ cvec,
                                                      const float* __restrict__ W1,
                                                      const float* __restrict__ E64b,
                                                      float* __restrict__ partial,
                                                      ushort16* __restrict__ hout) {
    __shared__ __align__(16) char Lraw[128 * 132 * 4];
    __shared__ float red[512];
    short* Wl = (short*)Lraw;
    short* Xl = (short*)(Lraw + 32768);
    float* H  = (float*)Lraw;

    const int t = threadIdx.x;
    const int nbase = blockIdx.x * 128;

    {
        int n = t & 127, kh = t >> 7;
        int nf = n >> 4, n16 = n & 15;
        #pragma unroll
        for (int q = 0; q < 8; ++q) {
            int kb = kh * 64 + q * 8;
            short pk[8];
            #pragma unroll
            for (int j = 0; j < 8; ++j)
                pk[j] = (short)f2bf(W1[(128 + kb + j) * 128 + n]);
            int s = kb >> 5, kg = (kb >> 3) & 3;
            *(short8v*)&Wl[(((nf * 4 + s) * 4 + kg) * 16 + n16) * 8] = *(short8v*)pk;
        }
    }
    {
        int k8 = t & 15, mg = t >> 4;
        f32x4 aA0 = *(const f32x4*)&A3[k8 * 8],       aA1 = *(const f32x4*)&A3[k8 * 8 + 4];
        f32x4 aB0 = *(const f32x4*)&A3[128 + k8 * 8], aB1 = *(const f32x4*)&A3[128 + k8 * 8 + 4];
        f32x4 aC0 = *(const f32x4*)&A3[256 + k8 * 8], aC1 = *(const f32x4*)&A3[256 + k8 * 8 + 4];
        f32x4 cv0 = *(const f32x4*)&cvec[k8 * 8],     cv1 = *(const f32x4*)&cvec[k8 * 8 + 4];
        int s = k8 >> 2, kg = k8 & 3;
        #pragma unroll
        for (int mm = 0; mm < 8; ++mm) {
            int m = mg * 8 + mm;
            const float* yy = y + (size_t)(nbase + m) * 3;
            float y0 = yy[0], y1 = yy[1], y2 = yy[2];
            short pk[8];
            #pragma unroll
            for (int j = 0; j < 4; ++j) {
                pk[j]     = (short)f2bf(lrelu(y0 * aA0[j] + y1 * aB0[j] + y2 * aC0[j] + cv0[j]));
                pk[4 + j] = (short)f2bf(lrelu(y0 * aA1[j] + y1 * aB1[j] + y2 * aC1[j] + cv1[j]));
            }
            *(short8v*)&Xl[(((m >> 4) * 4 + s) * 4 + kg) * 16 * 8 + (m & 15) * 8] = *(short8v*)pk;
        }
    }
    __syncthreads();

    const int w = t >> 6, l = t & 63;
    const int lk = l >> 4, l16 = l & 15;
    f32x4 acc[2][8];
    #pragma unroll
    for (int a = 0; a < 2; ++a)
        #pragma unroll
        for (int b = 0; b < 8; ++b) acc[a][b] = (f32x4)(0.f);
    #pragma unroll
    for (int s = 0; s < 4; ++s) {
        short8v af[2], bf[8];
        #pragma unroll
        for (int mf2 = 0; mf2 < 2; ++mf2) {
            int mf = w * 2 + mf2;
            af[mf2] = *(short8v*)&Xl[(((mf * 4 + s) * 4 + lk) * 16 + l16) * 8];
        }
        #pragma unroll
        for (int nf = 0; nf < 8; ++nf)
            bf[nf] = *(short8v*)&Wl[(((nf * 4 + s) * 4 + lk) * 16 + l16) * 8];
        #pragma unroll
        for (int mf2 = 0; mf2 < 2; ++mf2)
            #pragma unroll
            for (int nf = 0; nf < 8; ++nf)
                acc[mf2][nf] = __builtin_amdgcn_mfma_f32_16x16x32_bf16(af[mf2], bf[nf], acc[mf2][nf], 0, 0, 0);
    }
    __syncthreads();

    #pragma unroll
    for (int mf2 = 0; mf2 < 2; ++mf2) {
        int rbase = (w * 2 + mf2) * 16 + lk * 4;
        #pragma unroll
        for (int nf = 0; nf < 8; ++nf) {
            int c = nf * 16 + l16;
            #pragma unroll
            for (int r = 0; r < 4; ++r)
                H[(rbase + r) * 132 + c] = acc[mf2][nf][r];
        }
    }
    __syncthreads();

    {
        int m = t >> 1, ch = (t & 1) * 64;
        int node = nbase + m;
        int dg = deg[node];
        const float* Er = E64b + (size_t)dg * 128 + ch;
        #pragma unroll
        for (int q = 0; q < 8; ++q) {
            int c = ch + q * 8;
            f32x4 h0 = *(f32x4*)&H[m * 132 + c];
            f32x4 h1 = *(f32x4*)&H[m * 132 + c + 4];
            f32x4 e0 = *(const f32x4*)&Er[q * 8];
            f32x4 e1 = *(const f32x4*)&Er[q * 8 + 4];
            h0 += e0; h1 += e1;
            *(f32x4*)&H[m * 132 + c] = h0;
            *(f32x4*)&H[m * 132 + c + 4] = h1;
            uint32 pk[4];
            #pragma unroll
            for (int j = 0; j < 4; ++j) {
                float lo = (j < 2) ? h0[2 * j] : h1[2 * (j - 2)];
                float hi = (j < 2) ? h0[2 * j + 1] : h1[2 * (j - 2) + 1];
                pk[j] = (uint32)f2bf(lo) | ((uint32)f2bf(hi) << 16);
            }
            *(uint4*)&hout[(size_t)node * 128 + c] = *(uint4*)pk;
        }
    }
    __syncthreads();

    {
        int c2 = t & 127, nh = t >> 7;
        float ps = 0.f, pq = 0.f;
        #pragma unroll 8
        for (int i = 0; i < 64; ++i) {
            float v = H[(nh * 64 + i) * 132 + c2];
            ps += v; pq += v * v;
        }
        red[t] = ps; red[256 + t] = pq;
    }
    __syncthreads();
    if (t < 128) {
        float S = red[t] + red[t + 128];
        float Q = red[256 + t] + red[256 + t + 128];
        partial[(size_t)blockIdx.x * 256 + t] = S;
        partial[(size_t)blockIdx.x * 256 + 128 + t] = Q;
    }
}

// sum per-block partials -> stat2 (few atomics)
__global__ __launch_bounds__(256) void k_red(const float* __restrict__ partial,
                                             float* __restrict__ stat2) {
    int t = threadIdx.x;
    float s = 0.f;
    int rb = blockIdx.x * 64;
    for (int r = 0; r < 64; ++r) s += partial[(size_t)(rb + r) * 256 + t];
    atomicAdd(&stat2[t], s);
}

// fallback VALU k_main (MODE 1: stats only; MODE 2: final output)
template <int MODE>
__global__ __launch_bounds__(256, 2) void k_main(const float* __restrict__ y,
                                                 const int* __restrict__ deg,
                                                 const float* __restrict__ A3,
                                                 const float* __restrict__ cvec,
                                                 const float* __restrict__ W1,
                                                 const float* __restrict__ E64b,
                                                 float* __restrict__ stat2,
                                                 const float* __restrict__ sc2,
                                                 const float* __restrict__ sh2,
                                                 const float* __restrict__ W2,
                                                 const float* __restrict__ b2,
                                                 float* __restrict__ out) {
    __shared__ float Wl[128][128];
    __shared__ float xl[32][128];
    for (int i = threadIdx.x; i < 128 * 128; i += 256)
        Wl[i >> 7][i & 127] = W1[16384 + i];
    const int fg = threadIdx.x & 15;
    const int np = threadIdx.x >> 4;
    const int f0 = fg * 8;
    const int n0 = np * 2;
    const int fx = threadIdx.x & 127;
    const int nb = threadIdx.x >> 7;
    float a0 = A3[fx], a1 = A3[128 + fx], a2 = A3[256 + fx], cv = cvec[fx];
    float ssum[8] = {0}, ssq[8] = {0};
    float s2v[8], t2v[8], w2v[8], b2v = 0.f;
    if constexpr (MODE == 2) {
        *(float4*)&s2v[0] = *(const float4*)&sc2[f0];
        *(float4*)&s2v[4] = *(const float4*)&sc2[f0 + 4];
        *(float4*)&t2v[0] = *(const float4*)&sh2[f0];
        *(float4*)&t2v[4] = *(const float4*)&sh2[f0 + 4];
        *(float4*)&w2v[0] = *(const float4*)&W2[f0];
        *(float4*)&w2v[4] = *(const float4*)&W2[f0 + 4];
        b2v = b2[0];
    }
    for (int it = 0; it < 4; ++it) {
        int nbase = (blockIdx.x * 4 + it) * 32;
        __syncthreads();
        #pragma unroll
        for (int s = 0; s < 16; ++s) {
            int n = nb + s * 2;
            const float* yy = y + (nbase + n) * 3;
            float v = yy[0] * a0 + yy[1] * a1 + yy[2] * a2 + cv;
            xl[n][fx] = lrelu(v);
        }
        __syncthreads();
        float acc0[8] = {0}, acc1[8] = {0};
        for (int k4 = 0; k4 < 32; ++k4) {
            float xs0[4], xs1[4];
            *(float4*)xs0 = *(const float4*)&xl[n0][k4 * 4];
            *(float4*)xs1 = *(const float4*)&xl[n0 + 1][k4 * 4];
            #pragma unroll
            for (int kk = 0; kk < 4; ++kk) {
                float4 wA = *(const float4*)&Wl[k4 * 4 + kk][f0];
                float4 wB = *(const float4*)&Wl[k4 * 4 + kk][f0 + 4];
                float xa = xs0[kk], xb = xs1[kk];
                acc0[0] += xa * wA.x; acc0[1] += xa * wA.y; acc0[2] += xa * wA.z; acc0[3] += xa * wA.w;
                acc0[4] += xa * wB.x; acc0[5] += xa * wB.y; acc0[6] += xa * wB.z; acc0[7] += xa * wB.w;
                acc1[0] += xb * wA.x; acc1[1] += xb * wA.y; acc1[2] += xb * wA.z; acc1[3] += xb * wA.w;
                acc1[4] += xb * wB.x; acc1[5] += xb * wB.y; acc1[6] += xb * wB.z; acc1[7] += xb * wB.w;
            }
        }
        int nA = nbase + n0, nB = nA + 1;
        int dA = deg[nA], dB = deg[nB];
        float eA[8], eB[8], hA[8], hB[8];
        *(float4*)&eA[0] = *(const float4*)&E64b[dA * 128 + f0];
        *(float4*)&eA[4] = *(const float4*)&E64b[dA * 128 + f0 + 4];
        *(float4*)&eB[0] = *(const float4*)&E64b[dB * 128 + f0];
        *(float4*)&eB[4] = *(const float4*)&E64b[dB * 128 + f0 + 4];
        #pragma unroll
        for (int j = 0; j < 8; ++j) { hA[j] = acc0[j] + eA[j]; hB[j] = acc1[j] + eB[j]; }
        if constexpr (MODE == 1) {
            #pragma unroll
            for (int j = 0; j < 8; ++j) {
                ssum[j] += hA[j] + hB[j];
                ssq[j] += hA[j] * hA[j] + hB[j] * hB[j];
            }
        }
        if constexpr (MODE == 2) {
            float pA = 0.f, pB = 0.f;
            #pragma unroll
            for (int j = 0; j < 8; ++j) {
                pA += lrelu(hA[j] * s2v[j] + t2v[j]) * w2v[j];
                pB += lrelu(hB[j] * s2v[j] + t2v[j]) * w2v[j];
            }
            #pragma unroll
            for (int o = 1; o < 16; o <<= 1) {
                pA += __shfl_xor(pA, o, 64);
                pB += __shfl_xor(pB, o, 64);
            }
            if (fg == 0) {
                out[nA] = 1.f / (1.f + expf(-(pA + b2v)));
                out[nB] = 1.f / (1.f + expf(-(pB + b2v)));
            }
        }
    }
    if constexpr (MODE == 1) {
        __syncthreads();
        #pragma unroll
        for (int j = 0; j < 8; ++j) {
            ssum[j] += __shfl_xor(ssum[j], 16, 64);
            ssum[j] += __shfl_xor(ssum[j], 32, 64);
            ssq[j] += __shfl_xor(ssq[j], 16, 64);
            ssq[j] += __shfl_xor(ssq[j], 32, 64);
        }
        float* redp = &xl[0][0];
        int lane = threadIdx.x & 63, wid = threadIdx.x >> 6;
        if (lane < 16) {
            #pragma unroll
            for (int j = 0; j < 8; ++j) {
                redp[wid * 256 + lane * 16 + j] = ssum[j];
                redp[wid * 256 + lane * 16 + 8 + j] = ssq[j];
            }
        }
        __syncthreads();
        if (threadIdx.x < 128) {
            int d = threadIdx.x, fgg = d >> 3, j = d & 7;
            float s = redp[fgg * 16 + j] + redp[256 + fgg * 16 + j] +
                      redp[512 + fgg * 16 + j] + redp[768 + fgg * 16 + j];
            float q = redp[fgg * 16 + 8 + j] + redp[256 + fgg * 16 + 8 + j] +
                      redp[512 + fgg * 16 + 8 + j] + redp[768 + fgg * 16 + 8 + j];
            atomicAdd(&stat2[d], s);
            atomicAdd(&stat2[128 + d], q);
        }
    }
}

// K5: finalize BN2 scale/shift from stats
__global__ __launch_bounds__(128) void k_bn2(const float* __restrict__ stat2,
                                             const float* __restrict__ g2,
                                             const float* __restrict__ be2,
                                             float* __restrict__ sc2,
                                             float* __restrict__ sh2) {
    int d = threadIdx.x;
    float inv = 1.f / (float)N_NODES;
    float mu = stat2[d] * inv;
    float var = stat2[128 + d] * inv - mu * mu;
    float s = g2[d] * rsqrtf(var + 1e-5f);
    sc2[d] = s;
    sh2[d] = be2[d] - mu * s;
}

// K6: final elementwise from stored bf16 h
__global__ __launch_bounds__(256) void k_final_h(const ushort16* __restrict__ h,
                                                 const float* __restrict__ sc2,
                                                 const float* __restrict__ sh2,
                                                 const float* __restrict__ W2,
                                                 const float* __restrict__ b2,
                                                 float* __restrict__ out) {
    int t = blockIdx.x * 256 + threadIdx.x;
    int node = t >> 3, part = t & 7;
    const ushort16* hp = h + (size_t)node * 128 + part * 16;
    uint32 ua[4], ub[4];
    *(uint4*)ua = *(const uint4*)hp;
    *(uint4*)ub = *(const uint4*)(hp + 8);
    int fb = part * 16;
    float pd = 0.f;
    #pragma unroll
    for (int q = 0; q < 4; ++q) {
        int f = fb + 2 * q;
        float v0 = bf2f(ua[q] & 0xffffu), v1 = bf2f(ua[q] >> 16);
        pd += lrelu(v0 * sc2[f] + sh2[f]) * W2[f];
        pd += lrelu(v1 * sc2[f + 1] + sh2[f + 1]) * W2[f + 1];
        int g = fb + 8 + 2 * q;
        float w0 = bf2f(ub[q] & 0xffffu), w1 = bf2f(ub[q] >> 16);
        pd += lrelu(w0 * sc2[g] + sh2[g]) * W2[g];
        pd += lrelu(w1 * sc2[g + 1] + sh2[g + 1]) * W2[g + 1];
    }
    pd += __shfl_xor(pd, 1, 64);
    pd += __shfl_xor(pd, 2, 64);
    pd += __shfl_xor(pd, 4, 64);
    if (part == 0) out[node] = 1.f / (1.f + expf(-(pd + b2[0])));
}

extern "C" void kernel_launch(void* const* d_in, const int* in_sizes, int n_in,
                              void* d_out, int out_size, void* d_ws, size_t ws_size,
                              hipStream_t stream) {
    const int*   node_deg = (const int*)d_in[0];
    const int*   ei       = (const int*)d_in[1];
    const float* pos      = (const float*)d_in[2];
    const float* emb      = (const float*)d_in[3];
    const float* epsp     = (const float*)d_in[4];
    const float* Wc       = (const float*)d_in[5];
    const float* bc       = (const float*)d_in[6];
    const float* g1       = (const float*)d_in[7];
    const float* be1      = (const float*)d_in[8];
    const float* W1       = (const float*)d_in[9];
    const float* b1       = (const float*)d_in[10];
    const float* g2       = (const float*)d_in[11];
    const float* be2      = (const float*)d_in[12];
    const float* W2       = (const float*)d_in[13];
    const float* b2       = (const float*)d_in[14];
    float* out = (float*)d_out;

    float* F = (float*)d_ws;
    float* agg    = F;                    // 786432 (fallback agg; gemm partial)
    float* y      = F + 786432;           // 786432
    float* mom    = F + 1572864;          // 16
    float* stat2  = F + 1572880;          // 256
    float* A3     = F + 1573136;          // 384
    float* cvec   = F + 1573520;          // 128
    float* E64b   = F + 1573648;          // 8192
    float* sc2    = F + 1581840;          // 128
    float* sh2    = F + 1581968;          // 128
    uint32* bstart = (uint32*)(F + 1582096);  // 256 (1024 slots reserved)
    uint32* btot   = (uint32*)(F + 1583120);  // 256 (1024 slots reserved)
    float* U      = F + 1584144;          // overlay region
    uint32* binned   = (uint32*)U;                  // 8388608 u32 (33.5 MB)
    uint32* counts   = (uint32*)(U + 8388608);      // NBLK*NBKT = 262144 u32
    uint32* offsL    = (uint32*)(U + 8650752);      // 262144 u32
    float*  partialA = U + 8912896;                 // 4*256*3072 = 3145728 f32
    ushort16* hbuf   = (ushort16*)U;                // 64 MB, aliases all of the
                                                    // above (dead before gemm)
    // gemm's stat partial aliases the fallback agg region (dead by then);
    // round-4 lesson: it must NOT live inside hbuf.
    float* partial = agg;

    const size_t needBinH  = (size_t)(1584144 + 16777216) * 4;
    const size_t needBin   = (size_t)(1584144 + 12058624) * 4;
    bool useBin, storeH;
    if      (ws_size >= needBinH) { useBin = true;  storeH = true;  }
    else if (ws_size >= needBin)  { useBin = true;  storeH = false; }
    else                          { useBin = false; storeH = false; }

    hipMemsetAsync(mom, 0, 272 * 4, stream);  // mom + stat2 contiguous

    if (useBin) {
        k_hist<<<NBLK, 256, 0, stream>>>(ei, counts);
        k_scanB<<<NBKT, 256, 0, stream>>>(counts, offsL, btot);
        k_scanTot<<<1, 256, 0, stream>>>(btot, bstart);
        k_bin<<<NBLK, 256, 0, stream>>>(ei, offsL, bstart, binned);
        k_accum<<<NBKT * ACC_SPLIT, 256, 0, stream>>>(binned, bstart, btot, pos, partialA);
        k_y_moments<4><<<N_NODES / 256, 256, 0, stream>>>(pos, partialA, epsp, y, mom);
    } else {
        hipMemsetAsync(agg, 0, 786432 * 4, stream);
        k_scatter<<<N_EDGES / 256, 256, 0, stream>>>(ei, pos, agg);
        k_y_moments<1><<<N_NODES / 256, 256, 0, stream>>>(pos, agg, epsp, y, mom);
    }
    k_bn1<<<1, 128, 0, stream>>>(mom, Wc, bc, g1, be1, A3, cvec);
    k_e64<<<64, 128, 0, stream>>>(emb, W1, b1, E64b);

    if (storeH) {
        k_gemm_mfma<<<N_NODES / 128, 256, 0, stream>>>(y, node_deg, A3, cvec, W1,
                                                       E64b, partial, hbuf);
        k_red<<<32, 256, 0, stream>>>(partial, stat2);
        k_bn2<<<1, 128, 0, stream>>>(stat2, g2, be2, sc2, sh2);
        k_final_h<<<N_NODES / 32, 256, 0, stream>>>(hbuf, sc2, sh2, W2, b2, out);
    } else {
        k_main<1><<<2048, 256, 0, stream>>>(y, node_deg, A3, cvec, W1, E64b, stat2,
                                            nullptr, nullptr, nullptr, nullptr, nullptr);
        k_bn2<<<1, 128, 0, stream>>>(stat2, g2, be2, sc2, sh2);
        k_main<2><<<2048, 256, 0, stream>>>(y, node_deg, A3, cvec, W1, E64b, stat2,
                                            sc2, sh2, W2, b2, out);
    }
}